// Round 24
// baseline (3696.618 us; speedup 1.0000x reference)
//
#include <hip/hip_runtime.h>
#include <hip/hip_bf16.h>
#include <math.h>

// ---------------- problem dims ----------------
#define B_  64
#define N_  577
#define E_  768
#define D_  1024
#define L_  8
#define Q_  16
#define H_  16
#define DH_ 64
#define T_  320
#define FF_ 4096
#define O_  1024
#define MX_ (B_*N_)    // 36928 rows of x / xp
#define KL_ (N_+Q_)    // 593 kv rows per batch
#define BQ_ (B_*Q_)    // 1024 latent rows
#define KVOFF ((size_t)B_*H_*KL_*DH_)   // u16 elements between kbuf and vbuf

typedef unsigned short u16;
typedef __bf16 v8bf __attribute__((ext_vector_type(8)));
typedef float  v4f  __attribute__((ext_vector_type(4)));

__device__ __forceinline__ float bf2f(u16 u){
  union { float f; unsigned int i; } v; v.i = ((unsigned int)u) << 16; return v.f;
}
__device__ __forceinline__ u16 f2bf(float f){
  union { float f; unsigned int i; } v; v.f = f;
  unsigned int x = v.i;
  return (u16)((x + 0x7fffu + ((x >> 16) & 1u)) >> 16);  // RNE
}

// async global->LDS, 16B per lane; LDS dest = wave-uniform base + lane*16
__device__ __forceinline__ void gld16(const u16* g, u16* l){
  __builtin_amdgcn_global_load_lds(
      (const __attribute__((address_space(1))) void*)g,
      (__attribute__((address_space(3))) void*)l, 16, 0, 0);
}

// ---------------- timestep decode: int32 or int64 ----------------
__global__ void k_tsnorm(const int* __restrict__ raw, float* __restrict__ tsf){
  __shared__ int nz;
  int tid = threadIdx.x;  // 64
  if (tid == 0) nz = 0;
  __syncthreads();
  if (tid < 32 && raw[2 * tid + 1] != 0) atomicOr(&nz, 1);
  __syncthreads();
  int t = (nz == 0) ? raw[2 * tid] : raw[tid];
  tsf[tid] = (float)t;
}

// ---------------- fp32 -> bf16 conversion (vectorized) ----------------
__global__ void k_f2b(const float* __restrict__ src, u16* __restrict__ dst, long long n4){
  long long i = (long long)blockIdx.x * blockDim.x + threadIdx.x;
  long long stride = (long long)gridDim.x * blockDim.x;
  for (; i < n4; i += stride){
    float4 f = reinterpret_cast<const float4*>(src)[i];
    ushort4 u; u.x = f2bf(f.x); u.y = f2bf(f.y); u.z = f2bf(f.z); u.w = f2bf(f.w);
    reinterpret_cast<ushort4*>(dst)[i] = u;
  }
}

// ---------------- MFMA GEMM: C[M,N] = X[M,K] * W[N,K]^T (+epilogue) ----------------
// EPI: 0 bf16 | 2 +bias f32 | 3 +bias+temb bf16 | 4 +residual f32
//      5 GELU bf16 | 6 kv(x rows)+bias -> head-major K/V (out2=K base, V=+KVOFF)
//      7 +residual f32 AND bf16 copy (out2)
//      8 merged q + latent-kv: col<D -> qb (out), col>=D -> head-major K/V (out2)
// BM=128/BN=128/BK=32: ring-3 (48KB, 3 blocks/CU) - measured-best for kv/proj_in.
// BM=64 /BN=64 /BK=64: ring-4 (64KB, depth-3 pipeline) + setprio - latency-bound
//   small grids have no TLP; deeper ILP is the only latency hider.
// LPW == 4 for both -> counted vmcnt ladder 12/8/4/0 (ring-4) or 8/4/0 (ring-3).
template<int EPI, int BM, int BN>
__global__ __launch_bounds__(256) void k_gemm(
    const u16* __restrict__ X, const u16* __restrict__ Wm,
    const float* __restrict__ bias, const float* __restrict__ aux,
    void* __restrict__ out, void* __restrict__ out2, int M, int N, int K)
{
  constexpr int BK   = (BM == 128) ? 32 : 64;
  constexpr int WM   = BM / 2, WN = BN / 2;
  constexpr int MREP = WM / 16, NREP = WN / 16;
  constexpr int RPC  = 512 / BK;
  constexpr int NCHA = BM / RPC;
  constexpr int NCHB = BN / RPC;
  constexpr int NCH  = NCHA + NCHB;
  constexpr int LPW  = NCH / 4;
  static_assert(LPW == 4, "vmcnt ladder assumes LPW==4");
  constexpr int NBUF = (BM == 128) ? 3 : 4;
  __shared__ u16 As[NBUF * BM * BK];
  __shared__ u16 Bs[NBUF * BN * BK];
  const int tid  = threadIdx.x;
  const int lane = tid & 63;
  const int wid  = tid >> 6;
  const int wr   = wid >> 1, wc = wid & 1;
  const int m0   = blockIdx.y * BM, n0 = blockIdx.x * BN;
  const int fr   = lane & 15;
  const int js   = lane >> 4;
  const int fsw  = (fr >> 1) & ((BK == 32) ? 3 : 7);

  v4f zero = {0.f, 0.f, 0.f, 0.f};
  v4f acc[MREP][NREP];
  #pragma unroll
  for (int m = 0; m < MREP; ++m)
    #pragma unroll
    for (int n = 0; n < NREP; ++n) acc[m][n] = zero;

  int  aofs[LPW]; int loff[LPW]; bool isAv[LPW];
  #pragma unroll
  for (int p = 0; p < LPW; ++p) {
    const int ch = wid * LPW + p;
    const bool isA = (ch < NCHA);
    const int cb = isA ? ch : ch - NCHA;
    int grow, gc;
    if constexpr (BK == 32) {
      grow = cb * 16 + (lane >> 2);
      const int fst = (lane >> 3) & 3;
      gc = (((lane & 3) ^ fst) << 3);
    } else {
      grow = cb * 8 + (lane >> 3);
      const int fst = (cb * 4 + (lane >> 4)) & 7;
      gc = (((lane & 7) ^ fst) << 3);
    }
    isAv[p] = isA; loff[p] = cb * 512;
    if (isA) { int ar = m0 + grow; if (ar > M - 1) ar = M - 1; aofs[p] = ar * K + gc; }
    else     { int br = n0 + grow;                              aofs[p] = br * K + gc; }
  }

  auto stage = [&](int buf, int k0){
    const u16* Xk = X + k0;
    const u16* Wk = Wm + k0;
    #pragma unroll
    for (int p = 0; p < LPW; ++p) {
      if (isAv[p]) gld16(Xk + aofs[p], &As[buf * BM * BK + loff[p]]);
      else         gld16(Wk + aofs[p], &Bs[buf * BN * BK + loff[p]]);
    }
  };

  auto compute = [&](const u16* Ab, const u16* Bb){
    if constexpr (BM == 64) __builtin_amdgcn_s_setprio(1);
    #pragma unroll
    for (int kk = 0; kk < BK / 32; ++kk) {
      const int ps = (((kk * 4 + js) ^ fsw) << 3);
      v8bf a[MREP], b[NREP];
      #pragma unroll
      for (int m = 0; m < MREP; ++m)
        a[m] = *reinterpret_cast<const v8bf*>(Ab + (wr * WM + m * 16 + fr) * BK + ps);
      #pragma unroll
      for (int n = 0; n < NREP; ++n)
        b[n] = *reinterpret_cast<const v8bf*>(Bb + (wc * WN + n * 16 + fr) * BK + ps);
      #pragma unroll
      for (int m = 0; m < MREP; ++m)
        #pragma unroll
        for (int n = 0; n < NREP; ++n)
          acc[m][n] = __builtin_amdgcn_mfma_f32_16x16x32_bf16(a[m], b[n], acc[m][n], 0, 0, 0);
    }
    if constexpr (BM == 64) __builtin_amdgcn_s_setprio(0);
  };

  const int nt = K / BK;   // >= 16 at every call site (>= ring depth)
  #pragma unroll
  for (int i = 0; i < NBUF - 1; ++i) stage(i, i * BK);
  int bi = 0;
  for (int t = 0; t < nt; ++t) {
    if (t + NBUF - 1 < nt) {
      int sb = bi + NBUF - 1; if (sb >= NBUF) sb -= NBUF;
      stage(sb, (t + NBUF - 1) * BK);
    }
    // counted wait: leave 4 * (#future tiles in flight) outstanding; tile t done
    if constexpr (NBUF == 4) {
      if      (t + 3 < nt) asm volatile("s_waitcnt vmcnt(12)" ::: "memory");
      else if (t + 2 < nt) asm volatile("s_waitcnt vmcnt(8)"  ::: "memory");
      else if (t + 1 < nt) asm volatile("s_waitcnt vmcnt(4)"  ::: "memory");
      else                 asm volatile("s_waitcnt vmcnt(0)"  ::: "memory");
    } else {
      if      (t + 2 < nt) asm volatile("s_waitcnt vmcnt(8)"  ::: "memory");
      else if (t + 1 < nt) asm volatile("s_waitcnt vmcnt(4)"  ::: "memory");
      else                 asm volatile("s_waitcnt vmcnt(0)"  ::: "memory");
    }
    __builtin_amdgcn_s_barrier();      // all waves' tile-t loads landed
    compute(&As[bi * BM * BK], &Bs[bi * BN * BK]);
    __builtin_amdgcn_s_barrier();      // buf[t] reads done before its re-stage next iters
    ++bi; if (bi == NBUF) bi = 0;
  }

  const int rq = (lane >> 4) << 2;
  #pragma unroll
  for (int m = 0; m < MREP; ++m) {
    #pragma unroll
    for (int r = 0; r < 4; ++r) {
      const int row = m0 + wr * WM + m * 16 + rq + r;
      if (row >= M) continue;
      int bb6 = 0, jj6 = 0;
      if constexpr (EPI == 6) { bb6 = row / N_; jj6 = row - bb6 * N_; }
      #pragma unroll
      for (int n = 0; n < NREP; ++n) {
        const int col = n0 + wc * WN + n * 16 + fr;
        float v = acc[m][n][r];
        if constexpr (EPI == 2 || EPI == 3 || EPI == 6) v += bias[col];
        if constexpr (EPI == 3) v += aux[(size_t)(row / N_) * N + col];
        if constexpr (EPI == 4 || EPI == 7) v += aux[(size_t)row * N + col];
        if constexpr (EPI == 5) v = 0.5f * v * (1.0f + erff(v * 0.70710678118654752f));
        if constexpr (EPI == 6) {
          int c2 = (col < D_) ? col : col - D_;
          int hh = c2 >> 6, dd = c2 & 63;
          u16* dst = (u16*)out2 + ((col < D_) ? 0 : KVOFF);
          dst[(((size_t)bb6 * H_ + hh) * KL_ + jj6) * DH_ + dd] = f2bf(v);
        } else if constexpr (EPI == 8) {
          if (col < D_) {
            reinterpret_cast<u16*>(out)[(size_t)row * D_ + col] = f2bf(v);
          } else {
            int cc = col - D_;
            int bb = row >> 4, jj = N_ + (row & 15);
            int c2 = (cc < D_) ? cc : cc - D_;
            int hh = c2 >> 6, dd = c2 & 63;
            u16* dst = (u16*)out2 + ((cc < D_) ? 0 : KVOFF);
            dst[(((size_t)bb * H_ + hh) * KL_ + jj) * DH_ + dd] = f2bf(v);
          }
        } else if constexpr (EPI == 7) {
          reinterpret_cast<float*>(out)[(size_t)row * N + col] = v;
          reinterpret_cast<u16*>(out2)[(size_t)row * N + col] = f2bf(v);
        } else if constexpr (EPI == 2 || EPI == 4) {
          reinterpret_cast<float*>(out)[(size_t)row * N + col] = v;
        } else {
          reinterpret_cast<u16*>(out)[(size_t)row * N + col] = f2bf(v);
        }
      }
    }
  }
}

// ---------------- fused per-layer weight prep (ada batched pre-loop) ----------------
__global__ __launch_bounds__(256) void k_prep(
    const float* __restrict__ kvw, const float* __restrict__ g, const float* __restrict__ bvec,
    u16* __restrict__ kvf, u16* __restrict__ kvwb, float* __restrict__ kvb,
    const float* __restrict__ qw,  u16* __restrict__ dqw,
    const float* __restrict__ ow,  u16* __restrict__ dow,
    const float* __restrict__ f1w, u16* __restrict__ df1,
    const float* __restrict__ f2w, u16* __restrict__ df2)
{
  __shared__ float sl[4];
  const int bid = blockIdx.x, tid = threadIdx.x;
  if (bid < 2048) {
    int o = bid;
    float4 w = reinterpret_cast<const float4*>(kvw + (size_t)o * D_)[tid];
    float4 gg = reinterpret_cast<const float4*>(g)[tid];
    float4 bv = reinterpret_cast<const float4*>(bvec)[tid];
    ushort4 f;
    f.x = f2bf(w.x * gg.x); f.y = f2bf(w.y * gg.y); f.z = f2bf(w.z * gg.z); f.w = f2bf(w.w * gg.w);
    reinterpret_cast<ushort4*>(kvf + (size_t)o * D_)[tid] = f;
    ushort4 f2;
    f2.x = f2bf(w.x); f2.y = f2bf(w.y); f2.z = f2bf(w.z); f2.w = f2bf(w.w);
    reinterpret_cast<ushort4*>(kvwb + (size_t)o * D_)[tid] = f2;
    float s = w.x * bv.x + w.y * bv.y + w.z * bv.z + w.w * bv.w;
    for (int off = 32; off; off >>= 1) s += __shfl_down(s, off);
    if ((tid & 63) == 0) sl[tid >> 6] = s;
    __syncthreads();
    if (tid == 0) kvb[o] = sl[0] + sl[1] + sl[2] + sl[3];
  } else {
    int id = bid - 2048;
    const float* src; u16* dst; int off;
    if      (id < 1024)  { src = qw;  dst = dqw; off = id; }
    else if (id < 2048)  { src = ow;  dst = dow; off = id - 1024; }
    else if (id < 6144)  { src = f1w; dst = df1; off = id - 2048; }
    else                 { src = f2w; dst = df2; off = id - 6144; }
    size_t base = (size_t)off * 1024 + (size_t)tid * 4;
    float4 v = *reinterpret_cast<const float4*>(src + base);
    ushort4 u; u.x = f2bf(v.x); u.y = f2bf(v.y); u.z = f2bf(v.z); u.w = f2bf(v.w);
    *reinterpret_cast<ushort4*>(dst + base) = u;
  }
}

// ---------------- timestep embedding MLP ----------------
__global__ void k_temb1(const float* __restrict__ tsf, const float* __restrict__ w1,
                        const float* __restrict__ b1, float* __restrict__ h1tT){
  int o = blockIdx.x, b = threadIdx.x;  // 1024 x 64
  float t = tsf[b];
  float acc = b1[o];
  const float c = -9.210340371976184f / 160.0f;  // -ln(10000)/160
  for (int j = 0; j < 160; ++j) {
    float arg = t * expf(c * (float)j);
    acc += w1[(size_t)o * T_ + j] * cosf(arg) + w1[(size_t)o * T_ + 160 + j] * sinf(arg);
  }
  float s = acc / (1.0f + expf(-acc));
  h1tT[(size_t)o * B_ + b] = s;
}

__global__ void k_temb2(const float* __restrict__ h1tT, const float* __restrict__ w2,
                        const float* __restrict__ b2, float* __restrict__ temb){
  int o = blockIdx.x, b = threadIdx.x;  // 1024 x 64
  float acc = b2[o];
  for (int d = 0; d < D_; ++d) acc += h1tT[(size_t)d * B_ + b] * w2[(size_t)o * D_ + d];
  temb[(size_t)b * D_ + o] = acc;
}

__global__ void k_silu(const float* __restrict__ in, u16* __restrict__ outb, int n){
  int i = blockIdx.x * blockDim.x + threadIdx.x;
  if (i < n) { float x = in[i]; outb[i] = f2bf(x / (1.0f + expf(-x))); }
}

__global__ void k_init_lat(const float* __restrict__ latents, float* __restrict__ lat){
  int i = blockIdx.x * blockDim.x + threadIdx.x;
  if (i < BQ_ * D_) lat[i] = latents[i & (Q_ * D_ - 1)];
}

// ---------------- row LayerNorm (no affine), bf16 -> bf16 ----------------
__global__ __launch_bounds__(256) void k_rownorm(const u16* __restrict__ xp, u16* __restrict__ outb){
  __shared__ float s1[4], s2[4];
  size_t row = blockIdx.x;
  int tid = threadIdx.x;
  ushort4 u = reinterpret_cast<const ushort4*>(xp + row * D_)[tid];
  float v0 = bf2f(u.x), v1 = bf2f(u.y), v2 = bf2f(u.z), v3 = bf2f(u.w);
  float s = v0 + v1 + v2 + v3;
  float q = v0 * v0 + v1 * v1 + v2 * v2 + v3 * v3;
  for (int off = 32; off; off >>= 1) { s += __shfl_down(s, off); q += __shfl_down(q, off); }
  if ((tid & 63) == 0) { s1[tid >> 6] = s; s2[tid >> 6] = q; }
  __syncthreads();
  float S = s1[0] + s1[1] + s1[2] + s1[3], Qv = s2[0] + s2[1] + s2[2] + s2[3];
  float mean = S * (1.f / D_);
  float rs = rsqrtf(Qv * (1.f / D_) - mean * mean + 1e-5f);
  ushort4 o;
  o.x = f2bf((v0 - mean) * rs); o.y = f2bf((v1 - mean) * rs);
  o.z = f2bf((v2 - mean) * rs); o.w = f2bf((v3 - mean) * rs);
  reinterpret_cast<ushort4*>(outb + row * D_)[tid] = o;
}

// ---------------- LayerNorm + AdaLN modulation, fp32 -> bf16 ----------------
__global__ __launch_bounds__(256) void k_lnmod(const float* __restrict__ in, const float* __restrict__ g,
                                               const float* __restrict__ bb, const float* __restrict__ modp,
                                               int mstride, u16* __restrict__ outb){
  __shared__ float s1[4], s2[4];
  int row = blockIdx.x, tid = threadIdx.x;
  int b = row >> 4;
  float4 v = reinterpret_cast<const float4*>(in + (size_t)row * D_)[tid];
  float s = v.x + v.y + v.z + v.w;
  float q = v.x * v.x + v.y * v.y + v.z * v.z + v.w * v.w;
  for (int off = 32; off; off >>= 1) { s += __shfl_down(s, off); q += __shfl_down(q, off); }
  if ((tid & 63) == 0) { s1[tid >> 6] = s; s2[tid >> 6] = q; }
  __syncthreads();
  float S = s1[0] + s1[1] + s1[2] + s1[3], Qv = s2[0] + s2[1] + s2[2] + s2[3];
  float mean = S * (1.f / D_);
  float rs = rsqrtf(Qv * (1.f / D_) - mean * mean + 1e-5f);
  float4 gg = reinterpret_cast<const float4*>(g)[tid];
  float4 bv = reinterpret_cast<const float4*>(bb)[tid];
  const float* mrow = modp + (size_t)b * mstride;
  float4 sh = reinterpret_cast<const float4*>(mrow)[tid];
  float4 scv = reinterpret_cast<const float4*>(mrow + D_)[tid];
  ushort4 o;
  o.x = f2bf(((v.x - mean) * rs * gg.x + bv.x) * (1.f + scv.x) + sh.x);
  o.y = f2bf(((v.y - mean) * rs * gg.y + bv.y) * (1.f + scv.y) + sh.y);
  o.z = f2bf(((v.z - mean) * rs * gg.z + bv.z) * (1.f + scv.z) + sh.z);
  o.w = f2bf(((v.w - mean) * rs * gg.w + bv.w) * (1.f + scv.w) + sh.w);
  reinterpret_cast<ushort4*>(outb + (size_t)row * D_)[tid] = o;
}

// ---------------- final LayerNorm (affine), fp32 -> fp32 out ----------------
__global__ __launch_bounds__(256) void k_lnfinal(const float* __restrict__ in, const float* __restrict__ g,
                                                 const float* __restrict__ bb, float* __restrict__ outf){
  __shared__ float s1[4], s2[4];
  int row = blockIdx.x, tid = threadIdx.x;
  float4 v = reinterpret_cast<const float4*>(in + (size_t)row * O_)[tid];
  float s = v.x + v.y + v.z + v.w;
  float q = v.x * v.x + v.y * v.y + v.z * v.z + v.w * v.w;
  for (int off = 32; off; off >>= 1) { s += __shfl_down(s, off); q += __shfl_down(q, off); }
  if ((tid & 63) == 0) { s1[tid >> 6] = s; s2[tid >> 6] = q; }
  __syncthreads();
  float S = s1[0] + s1[1] + s1[2] + s1[3], Qv = s2[0] + s2[1] + s2[2] + s2[3];
  float mean = S * (1.f / O_);
  float rs = rsqrtf(Qv * (1.f / O_) - mean * mean + 1e-5f);
  float4 gg = reinterpret_cast<const float4*>(g)[tid];
  float4 bv = reinterpret_cast<const float4*>(bb)[tid];
  float4 o;
  o.x = (v.x - mean) * rs * gg.x + bv.x;
  o.y = (v.y - mean) * rs * gg.y + bv.y;
  o.z = (v.z - mean) * rs * gg.z + bv.z;
  o.w = (v.w - mean) * rs * gg.w + bv.w;
  reinterpret_cast<float4*>(outf + (size_t)row * O_)[tid] = o;
}

// ---------------- attention v3: head-major K/V, LDS-tiled QK^T AND PV ----------------
__global__ __launch_bounds__(256) void k_attn2(const u16* __restrict__ qb,
                                               const u16* __restrict__ kb,
                                               const u16* __restrict__ vb,
                                               u16* __restrict__ ob){
  __shared__ float qs[Q_][DH_ + 4];
  __shared__ u16   ks[128][DH_ + 4];   // K tile, reused as V tile in PV phase
  __shared__ float sc[Q_][600];
  __shared__ float rsum[Q_];
  const int bh  = blockIdx.x;           // b*16 + h
  const int b   = bh >> 4, h = bh & 15;
  const int tid = threadIdx.x;
  {
    int qi = tid >> 4, d4 = (tid & 15) << 2;
    ushort4 u = *reinterpret_cast<const ushort4*>(qb + (size_t)(b * Q_ + qi) * D_ + h * DH_ + d4);
    qs[qi][d4 + 0] = 0.125f * bf2f(u.x);   // sc*sc = 1/sqrt(DH) folded into Q
    qs[qi][d4 + 1] = 0.125f * bf2f(u.y);
    qs[qi][d4 + 2] = 0.125f * bf2f(u.z);
    qs[qi][d4 + 3] = 0.125f * bf2f(u.w);
  }
  const u16* kbh = kb + (size_t)bh * KL_ * DH_;
  const u16* vbh = vb + (size_t)bh * KL_ * DH_;
  for (int j0 = 0; j0 < KL_; j0 += 128) {
    int rows = KL_ - j0; if (rows > 128) rows = 128;
    __syncthreads();
    for (int idx = tid; idx < rows * 16; idx += 256) {
      int r = idx >> 4, c4 = (idx & 15) << 2;
      *reinterpret_cast<ushort4*>(&ks[r][c4]) =
          *reinterpret_cast<const ushort4*>(kbh + (size_t)(j0 + r) * DH_ + c4);
    }
    __syncthreads();
    for (int e = tid; e < Q_ * 128; e += 256) {
      int jj = e & 127, qi = e >> 7;
      if (jj < rows) {
        float s = 0.f;
        #pragma unroll
        for (int d = 0; d < DH_; d += 4) {
          ushort4 u = *reinterpret_cast<const ushort4*>(&ks[jj][d]);
          s += qs[qi][d] * bf2f(u.x) + qs[qi][d + 1] * bf2f(u.y)
             + qs[qi][d + 2] * bf2f(u.z) + qs[qi][d + 3] * bf2f(u.w);
        }
        sc[qi][j0 + jj] = s;
      }
    }
  }
  __syncthreads();
  {
    int g = tid >> 4, l = tid & 15;
    float mx = -1e30f;
    for (int j = l; j < KL_; j += 16) mx = fmaxf(mx, sc[g][j]);
    for (int m = 1; m < 16; m <<= 1) mx = fmaxf(mx, __shfl_xor(mx, m));
    float sum = 0.f;
    for (int j = l; j < KL_; j += 16) { float e = expf(sc[g][j] - mx); sc[g][j] = e; sum += e; }
    for (int m = 1; m < 16; m <<= 1) sum += __shfl_xor(sum, m);
    if (l == 0) rsum[g] = sum;
  }
  // PV phase: stage V tiles in LDS (reuse ks), accumulate
  {
    int d = tid & 63, q0 = tid >> 6;
    float acc[4] = {0.f, 0.f, 0.f, 0.f};
    for (int j0 = 0; j0 < KL_; j0 += 128) {
      int rows = KL_ - j0; if (rows > 128) rows = 128;
      __syncthreads();
      for (int idx = tid; idx < rows * 16; idx += 256) {
        int r = idx >> 4, c4 = (idx & 15) << 2;
        *reinterpret_cast<ushort4*>(&ks[r][c4]) =
            *reinterpret_cast<const ushort4*>(vbh + (size_t)(j0 + r) * DH_ + c4);
      }
      __syncthreads();
      for (int jj = 0; jj < rows; ++jj) {
        float vj = bf2f(ks[jj][d]);
        #pragma unroll
        for (int t = 0; t < 4; ++t) acc[t] += sc[q0 + t * 4][j0 + jj] * vj;
      }
    }
    #pragma unroll
    for (int t = 0; t < 4; ++t) {
      int qi = q0 + t * 4;
      ob[(size_t)(b * Q_ + qi) * D_ + h * DH_ + d] = f2bf(acc[t] / rsum[qi]);
    }
  }
}

// ---------------- host ----------------
static void conv_launch(const float* src, u16* dst, size_t n, hipStream_t s){
  long long n4 = (long long)(n >> 2);
  int blocks = (int)((n4 + 255) / 256);
  if (blocks > 4096) blocks = 4096;
  k_f2b<<<blocks, 256, 0, s>>>(src, dst, n4);
}

template<int EPI, int BM, int BN>
static void gemm(const u16* X, const u16* W, const float* bias, const float* aux,
                 void* out, void* out2, int M, int N, int K, hipStream_t s){
  dim3 g(N / BN, (M + BM - 1) / BM);
  k_gemm<EPI, BM, BN><<<g, 256, 0, s>>>(X, W, bias, aux, out, out2, M, N, K);
}

extern "C" void kernel_launch(void* const* d_in, const int* in_sizes, int n_in,
                              void* d_out, int out_size, void* d_ws, size_t ws_size,
                              hipStream_t stream)
{
  const float* x         = (const float*)d_in[0];
  const int*   tsp       = (const int*)  d_in[1];
  const float* latents   = (const float*)d_in[2];
  const float* proj_in_w = (const float*)d_in[3];
  const float* proj_in_b = (const float*)d_in[4];
  const float* time_w1   = (const float*)d_in[5];
  const float* time_b1   = (const float*)d_in[6];
  const float* time_w2   = (const float*)d_in[7];
  const float* time_b2   = (const float*)d_in[8];
  const float* ln1_g     = (const float*)d_in[9];
  const float* ln1_b     = (const float*)d_in[10];
  const float* ln2_g     = (const float*)d_in[11];
  const float* ln2_b     = (const float*)d_in[12];
  const float* q_w       = (const float*)d_in[13];
  const float* kv_w      = (const float*)d_in[14];
  const float* out_w     = (const float*)d_in[15];
  const float* ffln_g    = (const float*)d_in[16];
  const float* ffln_b    = (const float*)d_in[17];
  const float* ff_w1     = (const float*)d_in[18];
  const float* ff_w2     = (const float*)d_in[19];
  const float* ada_w     = (const float*)d_in[20];
  const float* ada_b     = (const float*)d_in[21];
  const float* proj_out_w= (const float*)d_in[22];
  const float* proj_out_b= (const float*)d_in[23];
  const float* nout_g    = (const float*)d_in[24];
  const float* nout_b    = (const float*)d_in[25];

  char* Wp = (char*)d_ws;
  size_t off = 0;
  auto alloc = [&](size_t bytes) -> void* {
    void* p = Wp + off;
    off = (off + bytes + 255) & ~(size_t)255;
    return p;
  };

  float* tsf   = (float*)alloc((size_t)B_ * 4);
  float* temb  = (float*)alloc((size_t)B_ * D_ * 4);
  float* h1tT  = (float*)alloc((size_t)D_ * B_ * 4);
  u16*   stemb = (u16*)  alloc((size_t)B_ * D_ * 2);
  float* modb8 = (float*)alloc((size_t)B_ * L_ * 4 * D_ * 4);   // [64][32768] all layers
  float* kvb   = (float*)alloc((size_t)2 * D_ * 4);
  float* lat   = (float*)alloc((size_t)BQ_ * D_ * 4);
  u16*   lt    = (u16*)  alloc((size_t)BQ_ * D_ * 2);
  u16*   qb    = (u16*)  alloc((size_t)BQ_ * D_ * 2);
  u16*   ob    = (u16*)  alloc((size_t)BQ_ * D_ * 2);
  u16*   hb    = (u16*)  alloc((size_t)BQ_ * D_ * 2);
  u16*   h1b   = (u16*)  alloc((size_t)BQ_ * FF_ * 2);
  u16*   latb  = (u16*)  alloc((size_t)BQ_ * D_ * 2);
  float* tmpf  = (float*)alloc((size_t)BQ_ * D_ * 4);
  u16*   wpin  = (u16*)  alloc((size_t)D_ * E_ * 2);
  u16*   wada8 = (u16*)  alloc((size_t)L_ * 4 * D_ * D_ * 2);   // all layers, bf16
  u16*   wpout = (u16*)  alloc((size_t)O_ * D_ * 2);
  u16*   kvf   = (u16*)  alloc((size_t)2 * D_ * D_ * 2);
  u16*   wqkv  = (u16*)  alloc((size_t)3 * D_ * D_ * 2);   // [q_w ; kv_w] stacked bf16
  u16*   wouti = (u16*)  alloc((size_t)D_ * D_ * 2);
  u16*   wff1i = (u16*)  alloc((size_t)FF_ * D_ * 2);
  u16*   wff2i = (u16*)  alloc((size_t)D_ * FF_ * 2);
  u16*   nxp   = (u16*)  alloc((size_t)MX_ * D_ * 2);
  u16*   kvwb  = wqkv + (size_t)D_ * D_;                   // rows 1024..3071 of wqkv
  // big region: prologue [xb | xpb], layer loop [kbuf | vbuf] (disjoint lifetimes)
  size_t xb_sz  = (size_t)B_ * N_ * E_ * 2;
  size_t xpb_sz = (size_t)MX_ * D_ * 2;
  size_t kv_sz  = (size_t)B_ * H_ * KL_ * DH_ * 2;
  size_t big_sz = (xb_sz + xpb_sz > 2 * kv_sz) ? (xb_sz + xpb_sz) : 2 * kv_sz;
  char* big = (char*)alloc(big_sz);
  u16* xb   = (u16*)big;
  u16* xpb  = (u16*)(big + xb_sz);
  u16* kbuf = (u16*)big;
  u16* vbuf = (u16*)(big + kv_sz);   // == kbuf + KVOFF elements

  // ---- weight / input conversions (layer-invariant) ----
  conv_launch(x,          xb,    (size_t)B_ * N_ * E_, stream);
  conv_launch(proj_in_w,  wpin,  (size_t)D_ * E_,      stream);
  conv_launch(proj_out_w, wpout, (size_t)O_ * D_,      stream);
  conv_launch(ada_w,      wada8, (size_t)L_ * 4 * D_ * D_, stream);

  // ---- timestep embedding ----
  k_tsnorm<<<1, B_, 0, stream>>>(tsp, tsf);
  k_temb1<<<D_, B_, 0, stream>>>(tsf, time_w1, time_b1, h1tT);
  k_temb2<<<D_, B_, 0, stream>>>(h1tT, time_w2, time_b2, temb);
  k_silu<<<(B_ * D_ + 255) / 256, 256, 0, stream>>>(temb, stemb, B_ * D_);

  // ---- AdaLN mod for ALL layers in one GEMM: [64, 32768] ----
  gemm<2, 64, 64>(stemb, wada8, ada_b, nullptr, modb8, nullptr, B_, L_ * 4 * D_, D_, stream);

  // ---- proj_in + temb ----
  gemm<3, 128, 128>(xb, wpin, proj_in_b, temb, xpb, nullptr, MX_, D_, E_, stream);
  k_rownorm<<<MX_, 256, 0, stream>>>(xpb, nxp);
  k_init_lat<<<(BQ_ * D_) / 256, 256, 0, stream>>>(latents, lat);

  const int MSTR = L_ * 4 * D_;   // 32768: per-batch row stride in modb8
  for (int i = 0; i < L_; ++i) {
    // fused per-layer weight prep (fold + 4 conversions)
    k_prep<<<12288, 256, 0, stream>>>(
        kv_w + (size_t)i * 2 * D_ * D_, ln1_g + i * D_, ln1_b + i * D_,
        kvf, kvwb, kvb,
        q_w   + (size_t)i * D_ * D_,  wqkv,
        out_w + (size_t)i * D_ * D_,  wouti,
        ff_w1 + (size_t)i * FF_ * D_, wff1i,
        ff_w2 + (size_t)i * D_ * FF_, wff2i);

    // kv over x tokens (dominant GEMM) -> head-major K/V, LN1 folded into weights
    gemm<6, 128, 128>(nxp, kvf, kvb, nullptr, nullptr, kbuf, MX_, 2 * D_, D_, stream);
    // modulated latents
    k_lnmod<<<BQ_, 256, 0, stream>>>(lat, ln2_g + i * D_, ln2_b + i * D_,
                                     modb8 + (size_t)i * 4 * D_, MSTR, lt);
    // merged q-proj + latent-kv: N = 3072
    gemm<8, 64, 64>(lt, wqkv, nullptr, nullptr, qb, kbuf, BQ_, 3 * D_, D_, stream);
    k_attn2<<<B_ * H_, 256, 0, stream>>>(qb, kbuf, vbuf, ob);
    gemm<4, 64, 64>(ob, wouti, nullptr, lat, lat, nullptr, BQ_, D_, D_, stream);
    // FFN
    k_lnmod<<<BQ_, 256, 0, stream>>>(lat, ffln_g + i * D_, ffln_b + i * D_,
                                     modb8 + (size_t)i * 4 * D_ + 2 * D_, MSTR, hb);
    gemm<5, 64, 64>(hb, wff1i, nullptr, nullptr, h1b, nullptr, BQ_, FF_, D_, stream);
    if (i < L_ - 1)
      gemm<4, 64, 64>(h1b, wff2i, nullptr, lat, lat, nullptr, BQ_, D_, FF_, stream);
    else  // last layer: also emit bf16 copy for the output projection
      gemm<7, 64, 64>(h1b, wff2i, nullptr, lat, lat, latb, BQ_, D_, FF_, stream);
  }

  // ---- output projection + final LN (fp32 output) ----
  gemm<2, 64, 64>(latb, wpout, proj_out_b, nullptr, tmpf, nullptr, BQ_, O_, D_, stream);
  k_lnfinal<<<BQ_, 256, 0, stream>>>(tmpf, nout_g, nout_b, (float*)d_out);
}

// Round 25
// 3668.217 us; speedup vs baseline: 1.0077x; 1.0077x over previous
//
#include <hip/hip_runtime.h>
#include <hip/hip_bf16.h>
#include <math.h>

// ---------------- problem dims ----------------
#define B_  64
#define N_  577
#define E_  768
#define D_  1024
#define L_  8
#define Q_  16
#define H_  16
#define DH_ 64
#define T_  320
#define FF_ 4096
#define O_  1024
#define MX_ (B_*N_)    // 36928 rows of x / xp
#define KL_ (N_+Q_)    // 593 kv rows per batch
#define BQ_ (B_*Q_)    // 1024 latent rows
#define KVOFF ((size_t)B_*H_*KL_*DH_)   // u16 elements between kbuf and vbuf

typedef unsigned short u16;
typedef __bf16 v8bf __attribute__((ext_vector_type(8)));
typedef float  v4f  __attribute__((ext_vector_type(4)));

__device__ __forceinline__ float bf2f(u16 u){
  union { float f; unsigned int i; } v; v.i = ((unsigned int)u) << 16; return v.f;
}
__device__ __forceinline__ u16 f2bf(float f){
  union { float f; unsigned int i; } v; v.f = f;
  unsigned int x = v.i;
  return (u16)((x + 0x7fffu + ((x >> 16) & 1u)) >> 16);  // RNE
}

// async global->LDS, 16B per lane; LDS dest = wave-uniform base + lane*16
__device__ __forceinline__ void gld16(const u16* g, u16* l){
  __builtin_amdgcn_global_load_lds(
      (const __attribute__((address_space(1))) void*)g,
      (__attribute__((address_space(3))) void*)l, 16, 0, 0);
}

// ---------------- timestep decode: int32 or int64 ----------------
__global__ void k_tsnorm(const int* __restrict__ raw, float* __restrict__ tsf){
  __shared__ int nz;
  int tid = threadIdx.x;  // 64
  if (tid == 0) nz = 0;
  __syncthreads();
  if (tid < 32 && raw[2 * tid + 1] != 0) atomicOr(&nz, 1);
  __syncthreads();
  int t = (nz == 0) ? raw[2 * tid] : raw[tid];
  tsf[tid] = (float)t;
}

// ---------------- fp32 -> bf16 conversion (vectorized) ----------------
__global__ void k_f2b(const float* __restrict__ src, u16* __restrict__ dst, long long n4){
  long long i = (long long)blockIdx.x * blockDim.x + threadIdx.x;
  long long stride = (long long)gridDim.x * blockDim.x;
  for (; i < n4; i += stride){
    float4 f = reinterpret_cast<const float4*>(src)[i];
    ushort4 u; u.x = f2bf(f.x); u.y = f2bf(f.y); u.z = f2bf(f.z); u.w = f2bf(f.w);
    reinterpret_cast<ushort4*>(dst)[i] = u;
  }
}

// ---------------- MFMA GEMM: C[M,N] = X[M,K] * W[N,K]^T (+epilogue) ----------------
// EPI: 0 bf16 | 2 +bias f32 | 3 +bias+temb bf16 | 4 +residual f32
//      5 GELU bf16 | 6 kv(x rows)+bias -> head-major K/V (out2=K base, V=+KVOFF)
//      7 +residual f32 AND bf16 copy (out2)
//      8 merged q + latent-kv: col<D -> qb (out), col>=D -> head-major K/V (out2)
// Ring-3 triple buffer (depth-2 pipeline) for BOTH tile paths (48KB LDS):
//   BM=128/BN=128/BK=32 (kv, proj_in) and BM=64/BN=64/BK=64 (small GEMMs, +setprio).
//   LPW == 4 for both -> vmcnt(8)/(4)/(0) ladder identical.
// Measured optimum of the family: depth 1 = 3.73ms, depth 2 = 3.67ms, depth 3 = 3.70ms.
template<int EPI, int BM, int BN>
__global__ __launch_bounds__(256) void k_gemm(
    const u16* __restrict__ X, const u16* __restrict__ Wm,
    const float* __restrict__ bias, const float* __restrict__ aux,
    void* __restrict__ out, void* __restrict__ out2, int M, int N, int K)
{
  constexpr int BK   = (BM == 128) ? 32 : 64;
  constexpr int WM   = BM / 2, WN = BN / 2;
  constexpr int MREP = WM / 16, NREP = WN / 16;
  constexpr int RPC  = 512 / BK;
  constexpr int NCHA = BM / RPC;
  constexpr int NCHB = BN / RPC;
  constexpr int NCH  = NCHA + NCHB;
  constexpr int LPW  = NCH / 4;
  static_assert(LPW == 4, "vmcnt ladder assumes LPW==4");
  __shared__ u16 As[3 * BM * BK];
  __shared__ u16 Bs[3 * BN * BK];
  const int tid  = threadIdx.x;
  const int lane = tid & 63;
  const int wid  = tid >> 6;
  const int wr   = wid >> 1, wc = wid & 1;
  const int m0   = blockIdx.y * BM, n0 = blockIdx.x * BN;
  const int fr   = lane & 15;
  const int js   = lane >> 4;
  const int fsw  = (fr >> 1) & ((BK == 32) ? 3 : 7);

  v4f zero = {0.f, 0.f, 0.f, 0.f};
  v4f acc[MREP][NREP];
  #pragma unroll
  for (int m = 0; m < MREP; ++m)
    #pragma unroll
    for (int n = 0; n < NREP; ++n) acc[m][n] = zero;

  int  aofs[LPW]; int loff[LPW]; bool isAv[LPW];
  #pragma unroll
  for (int p = 0; p < LPW; ++p) {
    const int ch = wid * LPW + p;
    const bool isA = (ch < NCHA);
    const int cb = isA ? ch : ch - NCHA;
    int grow, gc;
    if constexpr (BK == 32) {
      grow = cb * 16 + (lane >> 2);
      const int fst = (lane >> 3) & 3;
      gc = (((lane & 3) ^ fst) << 3);
    } else {
      grow = cb * 8 + (lane >> 3);
      const int fst = (cb * 4 + (lane >> 4)) & 7;
      gc = (((lane & 7) ^ fst) << 3);
    }
    isAv[p] = isA; loff[p] = cb * 512;
    if (isA) { int ar = m0 + grow; if (ar > M - 1) ar = M - 1; aofs[p] = ar * K + gc; }
    else     { int br = n0 + grow;                              aofs[p] = br * K + gc; }
  }

  auto stage = [&](int buf, int k0){
    const u16* Xk = X + k0;
    const u16* Wk = Wm + k0;
    #pragma unroll
    for (int p = 0; p < LPW; ++p) {
      if (isAv[p]) gld16(Xk + aofs[p], &As[buf * BM * BK + loff[p]]);
      else         gld16(Wk + aofs[p], &Bs[buf * BN * BK + loff[p]]);
    }
  };

  auto compute = [&](const u16* Ab, const u16* Bb){
    if constexpr (BM == 64) __builtin_amdgcn_s_setprio(1);
    #pragma unroll
    for (int kk = 0; kk < BK / 32; ++kk) {
      const int ps = (((kk * 4 + js) ^ fsw) << 3);
      v8bf a[MREP], b[NREP];
      #pragma unroll
      for (int m = 0; m < MREP; ++m)
        a[m] = *reinterpret_cast<const v8bf*>(Ab + (wr * WM + m * 16 + fr) * BK + ps);
      #pragma unroll
      for (int n = 0; n < NREP; ++n)
        b[n] = *reinterpret_cast<const v8bf*>(Bb + (wc * WN + n * 16 + fr) * BK + ps);
      #pragma unroll
      for (int m = 0; m < MREP; ++m)
        #pragma unroll
        for (int n = 0; n < NREP; ++n)
          acc[m][n] = __builtin_amdgcn_mfma_f32_16x16x32_bf16(a[m], b[n], acc[m][n], 0, 0, 0);
    }
    if constexpr (BM == 64) __builtin_amdgcn_s_setprio(0);
  };

  const int nt = K / BK;   // >= 16 at every call site (>= ring depth)
  stage(0, 0);
  stage(1, BK);
  int bi = 0;
  for (int t = 0; t < nt; ++t) {
    if (t + 2 < nt) {
      int sb = bi + 2; if (sb >= 3) sb -= 3;
      stage(sb, (t + 2) * BK);
      asm volatile("s_waitcnt vmcnt(8)" ::: "memory");   // tile t's 4 loads done
    } else if (t + 1 < nt) {
      asm volatile("s_waitcnt vmcnt(4)" ::: "memory");
    } else {
      asm volatile("s_waitcnt vmcnt(0)" ::: "memory");
    }
    __builtin_amdgcn_s_barrier();      // all waves' tile-t loads landed
    compute(&As[bi * BM * BK], &Bs[bi * BN * BK]);
    __builtin_amdgcn_s_barrier();      // buf[t] reads done before stage(t+3) next iter
    ++bi; if (bi == 3) bi = 0;
  }

  const int rq = (lane >> 4) << 2;
  #pragma unroll
  for (int m = 0; m < MREP; ++m) {
    #pragma unroll
    for (int r = 0; r < 4; ++r) {
      const int row = m0 + wr * WM + m * 16 + rq + r;
      if (row >= M) continue;
      int bb6 = 0, jj6 = 0;
      if constexpr (EPI == 6) { bb6 = row / N_; jj6 = row - bb6 * N_; }
      #pragma unroll
      for (int n = 0; n < NREP; ++n) {
        const int col = n0 + wc * WN + n * 16 + fr;
        float v = acc[m][n][r];
        if constexpr (EPI == 2 || EPI == 3 || EPI == 6) v += bias[col];
        if constexpr (EPI == 3) v += aux[(size_t)(row / N_) * N + col];
        if constexpr (EPI == 4 || EPI == 7) v += aux[(size_t)row * N + col];
        if constexpr (EPI == 5) v = 0.5f * v * (1.0f + erff(v * 0.70710678118654752f));
        if constexpr (EPI == 6) {
          int c2 = (col < D_) ? col : col - D_;
          int hh = c2 >> 6, dd = c2 & 63;
          u16* dst = (u16*)out2 + ((col < D_) ? 0 : KVOFF);
          dst[(((size_t)bb6 * H_ + hh) * KL_ + jj6) * DH_ + dd] = f2bf(v);
        } else if constexpr (EPI == 8) {
          if (col < D_) {
            reinterpret_cast<u16*>(out)[(size_t)row * D_ + col] = f2bf(v);
          } else {
            int cc = col - D_;
            int bb = row >> 4, jj = N_ + (row & 15);
            int c2 = (cc < D_) ? cc : cc - D_;
            int hh = c2 >> 6, dd = c2 & 63;
            u16* dst = (u16*)out2 + ((cc < D_) ? 0 : KVOFF);
            dst[(((size_t)bb * H_ + hh) * KL_ + jj) * DH_ + dd] = f2bf(v);
          }
        } else if constexpr (EPI == 7) {
          reinterpret_cast<float*>(out)[(size_t)row * N + col] = v;
          reinterpret_cast<u16*>(out2)[(size_t)row * N + col] = f2bf(v);
        } else if constexpr (EPI == 2 || EPI == 4) {
          reinterpret_cast<float*>(out)[(size_t)row * N + col] = v;
        } else {
          reinterpret_cast<u16*>(out)[(size_t)row * N + col] = f2bf(v);
        }
      }
    }
  }
}

// ---------------- fused per-layer weight prep (ada batched pre-loop) ----------------
__global__ __launch_bounds__(256) void k_prep(
    const float* __restrict__ kvw, const float* __restrict__ g, const float* __restrict__ bvec,
    u16* __restrict__ kvf, u16* __restrict__ kvwb, float* __restrict__ kvb,
    const float* __restrict__ qw,  u16* __restrict__ dqw,
    const float* __restrict__ ow,  u16* __restrict__ dow,
    const float* __restrict__ f1w, u16* __restrict__ df1,
    const float* __restrict__ f2w, u16* __restrict__ df2)
{
  __shared__ float sl[4];
  const int bid = blockIdx.x, tid = threadIdx.x;
  if (bid < 2048) {
    int o = bid;
    float4 w = reinterpret_cast<const float4*>(kvw + (size_t)o * D_)[tid];
    float4 gg = reinterpret_cast<const float4*>(g)[tid];
    float4 bv = reinterpret_cast<const float4*>(bvec)[tid];
    ushort4 f;
    f.x = f2bf(w.x * gg.x); f.y = f2bf(w.y * gg.y); f.z = f2bf(w.z * gg.z); f.w = f2bf(w.w * gg.w);
    reinterpret_cast<ushort4*>(kvf + (size_t)o * D_)[tid] = f;
    ushort4 f2;
    f2.x = f2bf(w.x); f2.y = f2bf(w.y); f2.z = f2bf(w.z); f2.w = f2bf(w.w);
    reinterpret_cast<ushort4*>(kvwb + (size_t)o * D_)[tid] = f2;
    float s = w.x * bv.x + w.y * bv.y + w.z * bv.z + w.w * bv.w;
    for (int off = 32; off; off >>= 1) s += __shfl_down(s, off);
    if ((tid & 63) == 0) sl[tid >> 6] = s;
    __syncthreads();
    if (tid == 0) kvb[o] = sl[0] + sl[1] + sl[2] + sl[3];
  } else {
    int id = bid - 2048;
    const float* src; u16* dst; int off;
    if      (id < 1024)  { src = qw;  dst = dqw; off = id; }
    else if (id < 2048)  { src = ow;  dst = dow; off = id - 1024; }
    else if (id < 6144)  { src = f1w; dst = df1; off = id - 2048; }
    else                 { src = f2w; dst = df2; off = id - 6144; }
    size_t base = (size_t)off * 1024 + (size_t)tid * 4;
    float4 v = *reinterpret_cast<const float4*>(src + base);
    ushort4 u; u.x = f2bf(v.x); u.y = f2bf(v.y); u.z = f2bf(v.z); u.w = f2bf(v.w);
    *reinterpret_cast<ushort4*>(dst + base) = u;
  }
}

// ---------------- timestep embedding MLP ----------------
__global__ void k_temb1(const float* __restrict__ tsf, const float* __restrict__ w1,
                        const float* __restrict__ b1, float* __restrict__ h1tT){
  int o = blockIdx.x, b = threadIdx.x;  // 1024 x 64
  float t = tsf[b];
  float acc = b1[o];
  const float c = -9.210340371976184f / 160.0f;  // -ln(10000)/160
  for (int j = 0; j < 160; ++j) {
    float arg = t * expf(c * (float)j);
    acc += w1[(size_t)o * T_ + j] * cosf(arg) + w1[(size_t)o * T_ + 160 + j] * sinf(arg);
  }
  float s = acc / (1.0f + expf(-acc));
  h1tT[(size_t)o * B_ + b] = s;
}

__global__ void k_temb2(const float* __restrict__ h1tT, const float* __restrict__ w2,
                        const float* __restrict__ b2, float* __restrict__ temb){
  int o = blockIdx.x, b = threadIdx.x;  // 1024 x 64
  float acc = b2[o];
  for (int d = 0; d < D_; ++d) acc += h1tT[(size_t)d * B_ + b] * w2[(size_t)o * D_ + d];
  temb[(size_t)b * D_ + o] = acc;
}

__global__ void k_silu(const float* __restrict__ in, u16* __restrict__ outb, int n){
  int i = blockIdx.x * blockDim.x + threadIdx.x;
  if (i < n) { float x = in[i]; outb[i] = f2bf(x / (1.0f + expf(-x))); }
}

__global__ void k_init_lat(const float* __restrict__ latents, float* __restrict__ lat){
  int i = blockIdx.x * blockDim.x + threadIdx.x;
  if (i < BQ_ * D_) lat[i] = latents[i & (Q_ * D_ - 1)];
}

// ---------------- row LayerNorm (no affine), bf16 -> bf16 ----------------
__global__ __launch_bounds__(256) void k_rownorm(const u16* __restrict__ xp, u16* __restrict__ outb){
  __shared__ float s1[4], s2[4];
  size_t row = blockIdx.x;
  int tid = threadIdx.x;
  ushort4 u = reinterpret_cast<const ushort4*>(xp + row * D_)[tid];
  float v0 = bf2f(u.x), v1 = bf2f(u.y), v2 = bf2f(u.z), v3 = bf2f(u.w);
  float s = v0 + v1 + v2 + v3;
  float q = v0 * v0 + v1 * v1 + v2 * v2 + v3 * v3;
  for (int off = 32; off; off >>= 1) { s += __shfl_down(s, off); q += __shfl_down(q, off); }
  if ((tid & 63) == 0) { s1[tid >> 6] = s; s2[tid >> 6] = q; }
  __syncthreads();
  float S = s1[0] + s1[1] + s1[2] + s1[3], Qv = s2[0] + s2[1] + s2[2] + s2[3];
  float mean = S * (1.f / D_);
  float rs = rsqrtf(Qv * (1.f / D_) - mean * mean + 1e-5f);
  ushort4 o;
  o.x = f2bf((v0 - mean) * rs); o.y = f2bf((v1 - mean) * rs);
  o.z = f2bf((v2 - mean) * rs); o.w = f2bf((v3 - mean) * rs);
  reinterpret_cast<ushort4*>(outb + row * D_)[tid] = o;
}

// ---------------- LayerNorm + AdaLN modulation, fp32 -> bf16 ----------------
__global__ __launch_bounds__(256) void k_lnmod(const float* __restrict__ in, const float* __restrict__ g,
                                               const float* __restrict__ bb, const float* __restrict__ modp,
                                               int mstride, u16* __restrict__ outb){
  __shared__ float s1[4], s2[4];
  int row = blockIdx.x, tid = threadIdx.x;
  int b = row >> 4;
  float4 v = reinterpret_cast<const float4*>(in + (size_t)row * D_)[tid];
  float s = v.x + v.y + v.z + v.w;
  float q = v.x * v.x + v.y * v.y + v.z * v.z + v.w * v.w;
  for (int off = 32; off; off >>= 1) { s += __shfl_down(s, off); q += __shfl_down(q, off); }
  if ((tid & 63) == 0) { s1[tid >> 6] = s; s2[tid >> 6] = q; }
  __syncthreads();
  float S = s1[0] + s1[1] + s1[2] + s1[3], Qv = s2[0] + s2[1] + s2[2] + s2[3];
  float mean = S * (1.f / D_);
  float rs = rsqrtf(Qv * (1.f / D_) - mean * mean + 1e-5f);
  float4 gg = reinterpret_cast<const float4*>(g)[tid];
  float4 bv = reinterpret_cast<const float4*>(bb)[tid];
  const float* mrow = modp + (size_t)b * mstride;
  float4 sh = reinterpret_cast<const float4*>(mrow)[tid];
  float4 scv = reinterpret_cast<const float4*>(mrow + D_)[tid];
  ushort4 o;
  o.x = f2bf(((v.x - mean) * rs * gg.x + bv.x) * (1.f + scv.x) + sh.x);
  o.y = f2bf(((v.y - mean) * rs * gg.y + bv.y) * (1.f + scv.y) + sh.y);
  o.z = f2bf(((v.z - mean) * rs * gg.z + bv.z) * (1.f + scv.z) + sh.z);
  o.w = f2bf(((v.w - mean) * rs * gg.w + bv.w) * (1.f + scv.w) + sh.w);
  reinterpret_cast<ushort4*>(outb + (size_t)row * D_)[tid] = o;
}

// ---------------- final LayerNorm (affine), fp32 -> fp32 out ----------------
__global__ __launch_bounds__(256) void k_lnfinal(const float* __restrict__ in, const float* __restrict__ g,
                                                 const float* __restrict__ bb, float* __restrict__ outf){
  __shared__ float s1[4], s2[4];
  int row = blockIdx.x, tid = threadIdx.x;
  float4 v = reinterpret_cast<const float4*>(in + (size_t)row * O_)[tid];
  float s = v.x + v.y + v.z + v.w;
  float q = v.x * v.x + v.y * v.y + v.z * v.z + v.w * v.w;
  for (int off = 32; off; off >>= 1) { s += __shfl_down(s, off); q += __shfl_down(q, off); }
  if ((tid & 63) == 0) { s1[tid >> 6] = s; s2[tid >> 6] = q; }
  __syncthreads();
  float S = s1[0] + s1[1] + s1[2] + s1[3], Qv = s2[0] + s2[1] + s2[2] + s2[3];
  float mean = S * (1.f / O_);
  float rs = rsqrtf(Qv * (1.f / O_) - mean * mean + 1e-5f);
  float4 gg = reinterpret_cast<const float4*>(g)[tid];
  float4 bv = reinterpret_cast<const float4*>(bb)[tid];
  float4 o;
  o.x = (v.x - mean) * rs * gg.x + bv.x;
  o.y = (v.y - mean) * rs * gg.y + bv.y;
  o.z = (v.z - mean) * rs * gg.z + bv.z;
  o.w = (v.w - mean) * rs * gg.w + bv.w;
  reinterpret_cast<float4*>(outf + (size_t)row * O_)[tid] = o;
}

// ---------------- attention v3: head-major K/V, LDS-tiled QK^T AND PV ----------------
__global__ __launch_bounds__(256) void k_attn2(const u16* __restrict__ qb,
                                               const u16* __restrict__ kb,
                                               const u16* __restrict__ vb,
                                               u16* __restrict__ ob){
  __shared__ float qs[Q_][DH_ + 4];
  __shared__ u16   ks[128][DH_ + 4];   // K tile, reused as V tile in PV phase
  __shared__ float sc[Q_][600];
  __shared__ float rsum[Q_];
  const int bh  = blockIdx.x;           // b*16 + h
  const int b   = bh >> 4, h = bh & 15;
  const int tid = threadIdx.x;
  {
    int qi = tid >> 4, d4 = (tid & 15) << 2;
    ushort4 u = *reinterpret_cast<const ushort4*>(qb + (size_t)(b * Q_ + qi) * D_ + h * DH_ + d4);
    qs[qi][d4 + 0] = 0.125f * bf2f(u.x);   // sc*sc = 1/sqrt(DH) folded into Q
    qs[qi][d4 + 1] = 0.125f * bf2f(u.y);
    qs[qi][d4 + 2] = 0.125f * bf2f(u.z);
    qs[qi][d4 + 3] = 0.125f * bf2f(u.w);
  }
  const u16* kbh = kb + (size_t)bh * KL_ * DH_;
  const u16* vbh = vb + (size_t)bh * KL_ * DH_;
  for (int j0 = 0; j0 < KL_; j0 += 128) {
    int rows = KL_ - j0; if (rows > 128) rows = 128;
    __syncthreads();
    for (int idx = tid; idx < rows * 16; idx += 256) {
      int r = idx >> 4, c4 = (idx & 15) << 2;
      *reinterpret_cast<ushort4*>(&ks[r][c4]) =
          *reinterpret_cast<const ushort4*>(kbh + (size_t)(j0 + r) * DH_ + c4);
    }
    __syncthreads();
    for (int e = tid; e < Q_ * 128; e += 256) {
      int jj = e & 127, qi = e >> 7;
      if (jj < rows) {
        float s = 0.f;
        #pragma unroll
        for (int d = 0; d < DH_; d += 4) {
          ushort4 u = *reinterpret_cast<const ushort4*>(&ks[jj][d]);
          s += qs[qi][d] * bf2f(u.x) + qs[qi][d + 1] * bf2f(u.y)
             + qs[qi][d + 2] * bf2f(u.z) + qs[qi][d + 3] * bf2f(u.w);
        }
        sc[qi][j0 + jj] = s;
      }
    }
  }
  __syncthreads();
  {
    int g = tid >> 4, l = tid & 15;
    float mx = -1e30f;
    for (int j = l; j < KL_; j += 16) mx = fmaxf(mx, sc[g][j]);
    for (int m = 1; m < 16; m <<= 1) mx = fmaxf(mx, __shfl_xor(mx, m));
    float sum = 0.f;
    for (int j = l; j < KL_; j += 16) { float e = expf(sc[g][j] - mx); sc[g][j] = e; sum += e; }
    for (int m = 1; m < 16; m <<= 1) sum += __shfl_xor(sum, m);
    if (l == 0) rsum[g] = sum;
  }
  // PV phase: stage V tiles in LDS (reuse ks), accumulate
  {
    int d = tid & 63, q0 = tid >> 6;
    float acc[4] = {0.f, 0.f, 0.f, 0.f};
    for (int j0 = 0; j0 < KL_; j0 += 128) {
      int rows = KL_ - j0; if (rows > 128) rows = 128;
      __syncthreads();
      for (int idx = tid; idx < rows * 16; idx += 256) {
        int r = idx >> 4, c4 = (idx & 15) << 2;
        *reinterpret_cast<ushort4*>(&ks[r][c4]) =
            *reinterpret_cast<const ushort4*>(vbh + (size_t)(j0 + r) * DH_ + c4);
      }
      __syncthreads();
      for (int jj = 0; jj < rows; ++jj) {
        float vj = bf2f(ks[jj][d]);
        #pragma unroll
        for (int t = 0; t < 4; ++t) acc[t] += sc[q0 + t * 4][j0 + jj] * vj;
      }
    }
    #pragma unroll
    for (int t = 0; t < 4; ++t) {
      int qi = q0 + t * 4;
      ob[(size_t)(b * Q_ + qi) * D_ + h * DH_ + d] = f2bf(acc[t] / rsum[qi]);
    }
  }
}

// ---------------- host ----------------
static void conv_launch(const float* src, u16* dst, size_t n, hipStream_t s){
  long long n4 = (long long)(n >> 2);
  int blocks = (int)((n4 + 255) / 256);
  if (blocks > 4096) blocks = 4096;
  k_f2b<<<blocks, 256, 0, s>>>(src, dst, n4);
}

template<int EPI, int BM, int BN>
static void gemm(const u16* X, const u16* W, const float* bias, const float* aux,
                 void* out, void* out2, int M, int N, int K, hipStream_t s){
  dim3 g(N / BN, (M + BM - 1) / BM);
  k_gemm<EPI, BM, BN><<<g, 256, 0, s>>>(X, W, bias, aux, out, out2, M, N, K);
}

extern "C" void kernel_launch(void* const* d_in, const int* in_sizes, int n_in,
                              void* d_out, int out_size, void* d_ws, size_t ws_size,
                              hipStream_t stream)
{
  const float* x         = (const float*)d_in[0];
  const int*   tsp       = (const int*)  d_in[1];
  const float* latents   = (const float*)d_in[2];
  const float* proj_in_w = (const float*)d_in[3];
  const float* proj_in_b = (const float*)d_in[4];
  const float* time_w1   = (const float*)d_in[5];
  const float* time_b1   = (const float*)d_in[6];
  const float* time_w2   = (const float*)d_in[7];
  const float* time_b2   = (const float*)d_in[8];
  const float* ln1_g     = (const float*)d_in[9];
  const float* ln1_b     = (const float*)d_in[10];
  const float* ln2_g     = (const float*)d_in[11];
  const float* ln2_b     = (const float*)d_in[12];
  const float* q_w       = (const float*)d_in[13];
  const float* kv_w      = (const float*)d_in[14];
  const float* out_w     = (const float*)d_in[15];
  const float* ffln_g    = (const float*)d_in[16];
  const float* ffln_b    = (const float*)d_in[17];
  const float* ff_w1     = (const float*)d_in[18];
  const float* ff_w2     = (const float*)d_in[19];
  const float* ada_w     = (const float*)d_in[20];
  const float* ada_b     = (const float*)d_in[21];
  const float* proj_out_w= (const float*)d_in[22];
  const float* proj_out_b= (const float*)d_in[23];
  const float* nout_g    = (const float*)d_in[24];
  const float* nout_b    = (const float*)d_in[25];

  char* Wp = (char*)d_ws;
  size_t off = 0;
  auto alloc = [&](size_t bytes) -> void* {
    void* p = Wp + off;
    off = (off + bytes + 255) & ~(size_t)255;
    return p;
  };

  float* tsf   = (float*)alloc((size_t)B_ * 4);
  float* temb  = (float*)alloc((size_t)B_ * D_ * 4);
  float* h1tT  = (float*)alloc((size_t)D_ * B_ * 4);
  u16*   stemb = (u16*)  alloc((size_t)B_ * D_ * 2);
  float* modb8 = (float*)alloc((size_t)B_ * L_ * 4 * D_ * 4);   // [64][32768] all layers
  float* kvb   = (float*)alloc((size_t)2 * D_ * 4);
  float* lat   = (float*)alloc((size_t)BQ_ * D_ * 4);
  u16*   lt    = (u16*)  alloc((size_t)BQ_ * D_ * 2);
  u16*   qb    = (u16*)  alloc((size_t)BQ_ * D_ * 2);
  u16*   ob    = (u16*)  alloc((size_t)BQ_ * D_ * 2);
  u16*   hb    = (u16*)  alloc((size_t)BQ_ * D_ * 2);
  u16*   h1b   = (u16*)  alloc((size_t)BQ_ * FF_ * 2);
  u16*   latb  = (u16*)  alloc((size_t)BQ_ * D_ * 2);
  float* tmpf  = (float*)alloc((size_t)BQ_ * D_ * 4);
  u16*   wpin  = (u16*)  alloc((size_t)D_ * E_ * 2);
  u16*   wada8 = (u16*)  alloc((size_t)L_ * 4 * D_ * D_ * 2);   // all layers, bf16
  u16*   wpout = (u16*)  alloc((size_t)O_ * D_ * 2);
  u16*   kvf   = (u16*)  alloc((size_t)2 * D_ * D_ * 2);
  u16*   wqkv  = (u16*)  alloc((size_t)3 * D_ * D_ * 2);   // [q_w ; kv_w] stacked bf16
  u16*   wouti = (u16*)  alloc((size_t)D_ * D_ * 2);
  u16*   wff1i = (u16*)  alloc((size_t)FF_ * D_ * 2);
  u16*   wff2i = (u16*)  alloc((size_t)D_ * FF_ * 2);
  u16*   nxp   = (u16*)  alloc((size_t)MX_ * D_ * 2);
  u16*   kvwb  = wqkv + (size_t)D_ * D_;                   // rows 1024..3071 of wqkv
  // big region: prologue [xb | xpb], layer loop [kbuf | vbuf] (disjoint lifetimes)
  size_t xb_sz  = (size_t)B_ * N_ * E_ * 2;
  size_t xpb_sz = (size_t)MX_ * D_ * 2;
  size_t kv_sz  = (size_t)B_ * H_ * KL_ * DH_ * 2;
  size_t big_sz = (xb_sz + xpb_sz > 2 * kv_sz) ? (xb_sz + xpb_sz) : 2 * kv_sz;
  char* big = (char*)alloc(big_sz);
  u16* xb   = (u16*)big;
  u16* xpb  = (u16*)(big + xb_sz);
  u16* kbuf = (u16*)big;
  u16* vbuf = (u16*)(big + kv_sz);   // == kbuf + KVOFF elements

  // ---- weight / input conversions (layer-invariant) ----
  conv_launch(x,          xb,    (size_t)B_ * N_ * E_, stream);
  conv_launch(proj_in_w,  wpin,  (size_t)D_ * E_,      stream);
  conv_launch(proj_out_w, wpout, (size_t)O_ * D_,      stream);
  conv_launch(ada_w,      wada8, (size_t)L_ * 4 * D_ * D_, stream);

  // ---- timestep embedding ----
  k_tsnorm<<<1, B_, 0, stream>>>(tsp, tsf);
  k_temb1<<<D_, B_, 0, stream>>>(tsf, time_w1, time_b1, h1tT);
  k_temb2<<<D_, B_, 0, stream>>>(h1tT, time_w2, time_b2, temb);
  k_silu<<<(B_ * D_ + 255) / 256, 256, 0, stream>>>(temb, stemb, B_ * D_);

  // ---- AdaLN mod for ALL layers in one GEMM: [64, 32768] ----
  gemm<2, 64, 64>(stemb, wada8, ada_b, nullptr, modb8, nullptr, B_, L_ * 4 * D_, D_, stream);

  // ---- proj_in + temb ----
  gemm<3, 128, 128>(xb, wpin, proj_in_b, temb, xpb, nullptr, MX_, D_, E_, stream);
  k_rownorm<<<MX_, 256, 0, stream>>>(xpb, nxp);
  k_init_lat<<<(BQ_ * D_) / 256, 256, 0, stream>>>(latents, lat);

  const int MSTR = L_ * 4 * D_;   // 32768: per-batch row stride in modb8
  for (int i = 0; i < L_; ++i) {
    // fused per-layer weight prep (fold + 4 conversions)
    k_prep<<<12288, 256, 0, stream>>>(
        kv_w + (size_t)i * 2 * D_ * D_, ln1_g + i * D_, ln1_b + i * D_,
        kvf, kvwb, kvb,
        q_w   + (size_t)i * D_ * D_,  wqkv,
        out_w + (size_t)i * D_ * D_,  wouti,
        ff_w1 + (size_t)i * FF_ * D_, wff1i,
        ff_w2 + (size_t)i * D_ * FF_, wff2i);

    // kv over x tokens (dominant GEMM) -> head-major K/V, LN1 folded into weights
    gemm<6, 128, 128>(nxp, kvf, kvb, nullptr, nullptr, kbuf, MX_, 2 * D_, D_, stream);
    // modulated latents
    k_lnmod<<<BQ_, 256, 0, stream>>>(lat, ln2_g + i * D_, ln2_b + i * D_,
                                     modb8 + (size_t)i * 4 * D_, MSTR, lt);
    // merged q-proj + latent-kv: N = 3072
    gemm<8, 64, 64>(lt, wqkv, nullptr, nullptr, qb, kbuf, BQ_, 3 * D_, D_, stream);
    k_attn2<<<B_ * H_, 256, 0, stream>>>(qb, kbuf, vbuf, ob);
    gemm<4, 64, 64>(ob, wouti, nullptr, lat, lat, nullptr, BQ_, D_, D_, stream);
    // FFN
    k_lnmod<<<BQ_, 256, 0, stream>>>(lat, ffln_g + i * D_, ffln_b + i * D_,
                                     modb8 + (size_t)i * 4 * D_ + 2 * D_, MSTR, hb);
    gemm<5, 64, 64>(hb, wff1i, nullptr, nullptr, h1b, nullptr, BQ_, FF_, D_, stream);
    if (i < L_ - 1)
      gemm<4, 64, 64>(h1b, wff2i, nullptr, lat, lat, nullptr, BQ_, D_, FF_, stream);
    else  // last layer: also emit bf16 copy for the output projection
      gemm<7, 64, 64>(h1b, wff2i, nullptr, lat, lat, latb, BQ_, D_, FF_, stream);
  }

  // ---- output projection + final LN (fp32 output) ----
  gemm<2, 64, 64>(latb, wpout, proj_out_b, nullptr, tmpf, nullptr, BQ_, O_, D_, stream);
  k_lnfinal<<<BQ_, 256, 0, stream>>>(tmpf, nout_g, nout_b, (float*)d_out);
}

// Round 26
// 3663.440 us; speedup vs baseline: 1.0091x; 1.0013x over previous
//
#include <hip/hip_runtime.h>
#include <hip/hip_bf16.h>
#include <math.h>

// ---------------- problem dims ----------------
#define B_  64
#define N_  577
#define E_  768
#define D_  1024
#define L_  8
#define Q_  16
#define H_  16
#define DH_ 64
#define T_  320
#define FF_ 4096
#define O_  1024
#define MX_ (B_*N_)    // 36928 rows of x / xp
#define KL_ (N_+Q_)    // 593 kv rows per batch
#define BQ_ (B_*Q_)    // 1024 latent rows
#define KVOFF ((size_t)B_*H_*KL_*DH_)   // u16 elements between kbuf and vbuf

typedef unsigned short u16;
typedef __bf16 v8bf __attribute__((ext_vector_type(8)));
typedef float  v4f  __attribute__((ext_vector_type(4)));

__device__ __forceinline__ float bf2f(u16 u){
  union { float f; unsigned int i; } v; v.i = ((unsigned int)u) << 16; return v.f;
}
__device__ __forceinline__ u16 f2bf(float f){
  union { float f; unsigned int i; } v; v.f = f;
  unsigned int x = v.i;
  return (u16)((x + 0x7fffu + ((x >> 16) & 1u)) >> 16);  // RNE
}

// async global->LDS, 16B per lane; LDS dest = wave-uniform base + lane*16
__device__ __forceinline__ void gld16(const u16* g, u16* l){
  __builtin_amdgcn_global_load_lds(
      (const __attribute__((address_space(1))) void*)g,
      (__attribute__((address_space(3))) void*)l, 16, 0, 0);
}

// ---------------- timestep decode: int32 or int64 ----------------
__global__ void k_tsnorm(const int* __restrict__ raw, float* __restrict__ tsf){
  __shared__ int nz;
  int tid = threadIdx.x;  // 64
  if (tid == 0) nz = 0;
  __syncthreads();
  if (tid < 32 && raw[2 * tid + 1] != 0) atomicOr(&nz, 1);
  __syncthreads();
  int t = (nz == 0) ? raw[2 * tid] : raw[tid];
  tsf[tid] = (float)t;
}

// ---------------- fp32 -> bf16 conversion (vectorized) ----------------
__global__ void k_f2b(const float* __restrict__ src, u16* __restrict__ dst, long long n4){
  long long i = (long long)blockIdx.x * blockDim.x + threadIdx.x;
  long long stride = (long long)gridDim.x * blockDim.x;
  for (; i < n4; i += stride){
    float4 f = reinterpret_cast<const float4*>(src)[i];
    ushort4 u; u.x = f2bf(f.x); u.y = f2bf(f.y); u.z = f2bf(f.z); u.w = f2bf(f.w);
    reinterpret_cast<ushort4*>(dst)[i] = u;
  }
}

// ---------------- MFMA GEMM: C[M,N] = X[M,K] * W[N,K]^T (+epilogue) ----------------
// EPI: 0 bf16 | 2 +bias f32 | 3 +bias+temb bf16 | 4 +residual f32
//      5 GELU bf16 | 6 kv(x rows)+bias -> head-major K/V (out2=K base, V=+KVOFF)
//      7 +residual f32 AND bf16 copy (out2)
//      8 merged q + latent-kv: col<D -> qb (out), col>=D -> head-major K/V (out2)
// Ring-3 triple buffer (depth-2 pipeline) for BOTH tile paths (48KB LDS):
//   BM=128/BN=128/BK=32 (kv, proj_in) and BM=64/BN=64/BK=64 (small GEMMs, +setprio).
//   LPW == 4 for both -> vmcnt(8)/(4)/(0) ladder identical.
// Measured optimum of the family: depth 1 = 3.73ms, depth 2 = 3.67ms, depth 3 = 3.70ms.
template<int EPI, int BM, int BN>
__global__ __launch_bounds__(256) void k_gemm(
    const u16* __restrict__ X, const u16* __restrict__ Wm,
    const float* __restrict__ bias, const float* __restrict__ aux,
    void* __restrict__ out, void* __restrict__ out2, int M, int N, int K)
{
  constexpr int BK   = (BM == 128) ? 32 : 64;
  constexpr int WM   = BM / 2, WN = BN / 2;
  constexpr int MREP = WM / 16, NREP = WN / 16;
  constexpr int RPC  = 512 / BK;
  constexpr int NCHA = BM / RPC;
  constexpr int NCHB = BN / RPC;
  constexpr int NCH  = NCHA + NCHB;
  constexpr int LPW  = NCH / 4;
  static_assert(LPW == 4, "vmcnt ladder assumes LPW==4");
  __shared__ u16 As[3 * BM * BK];
  __shared__ u16 Bs[3 * BN * BK];
  const int tid  = threadIdx.x;
  const int lane = tid & 63;
  const int wid  = tid >> 6;
  const int wr   = wid >> 1, wc = wid & 1;
  const int m0   = blockIdx.y * BM, n0 = blockIdx.x * BN;
  const int fr   = lane & 15;
  const int js   = lane >> 4;
  const int fsw  = (fr >> 1) & ((BK == 32) ? 3 : 7);

  v4f zero = {0.f, 0.f, 0.f, 0.f};
  v4f acc[MREP][NREP];
  #pragma unroll
  for (int m = 0; m < MREP; ++m)
    #pragma unroll
    for (int n = 0; n < NREP; ++n) acc[m][n] = zero;

  int  aofs[LPW]; int loff[LPW]; bool isAv[LPW];
  #pragma unroll
  for (int p = 0; p < LPW; ++p) {
    const int ch = wid * LPW + p;
    const bool isA = (ch < NCHA);
    const int cb = isA ? ch : ch - NCHA;
    int grow, gc;
    if constexpr (BK == 32) {
      grow = cb * 16 + (lane >> 2);
      const int fst = (lane >> 3) & 3;
      gc = (((lane & 3) ^ fst) << 3);
    } else {
      grow = cb * 8 + (lane >> 3);
      const int fst = (cb * 4 + (lane >> 4)) & 7;
      gc = (((lane & 7) ^ fst) << 3);
    }
    isAv[p] = isA; loff[p] = cb * 512;
    if (isA) { int ar = m0 + grow; if (ar > M - 1) ar = M - 1; aofs[p] = ar * K + gc; }
    else     { int br = n0 + grow;                              aofs[p] = br * K + gc; }
  }

  auto stage = [&](int buf, int k0){
    const u16* Xk = X + k0;
    const u16* Wk = Wm + k0;
    #pragma unroll
    for (int p = 0; p < LPW; ++p) {
      if (isAv[p]) gld16(Xk + aofs[p], &As[buf * BM * BK + loff[p]]);
      else         gld16(Wk + aofs[p], &Bs[buf * BN * BK + loff[p]]);
    }
  };

  auto compute = [&](const u16* Ab, const u16* Bb){
    if constexpr (BM == 64) __builtin_amdgcn_s_setprio(1);
    #pragma unroll
    for (int kk = 0; kk < BK / 32; ++kk) {
      const int ps = (((kk * 4 + js) ^ fsw) << 3);
      v8bf a[MREP], b[NREP];
      #pragma unroll
      for (int m = 0; m < MREP; ++m)
        a[m] = *reinterpret_cast<const v8bf*>(Ab + (wr * WM + m * 16 + fr) * BK + ps);
      #pragma unroll
      for (int n = 0; n < NREP; ++n)
        b[n] = *reinterpret_cast<const v8bf*>(Bb + (wc * WN + n * 16 + fr) * BK + ps);
      #pragma unroll
      for (int m = 0; m < MREP; ++m)
        #pragma unroll
        for (int n = 0; n < NREP; ++n)
          acc[m][n] = __builtin_amdgcn_mfma_f32_16x16x32_bf16(a[m], b[n], acc[m][n], 0, 0, 0);
    }
    if constexpr (BM == 64) __builtin_amdgcn_s_setprio(0);
  };

  const int nt = K / BK;   // >= 16 at every call site (>= ring depth)
  stage(0, 0);
  stage(1, BK);
  int bi = 0;
  for (int t = 0; t < nt; ++t) {
    if (t + 2 < nt) {
      int sb = bi + 2; if (sb >= 3) sb -= 3;
      stage(sb, (t + 2) * BK);
      asm volatile("s_waitcnt vmcnt(8)" ::: "memory");   // tile t's 4 loads done
    } else if (t + 1 < nt) {
      asm volatile("s_waitcnt vmcnt(4)" ::: "memory");
    } else {
      asm volatile("s_waitcnt vmcnt(0)" ::: "memory");
    }
    __builtin_amdgcn_s_barrier();      // all waves' tile-t loads landed
    compute(&As[bi * BM * BK], &Bs[bi * BN * BK]);
    __builtin_amdgcn_s_barrier();      // buf[t] reads done before stage(t+3) next iter
    ++bi; if (bi == 3) bi = 0;
  }

  const int rq = (lane >> 4) << 2;
  #pragma unroll
  for (int m = 0; m < MREP; ++m) {
    #pragma unroll
    for (int r = 0; r < 4; ++r) {
      const int row = m0 + wr * WM + m * 16 + rq + r;
      if (row >= M) continue;
      int bb6 = 0, jj6 = 0;
      if constexpr (EPI == 6) { bb6 = row / N_; jj6 = row - bb6 * N_; }
      #pragma unroll
      for (int n = 0; n < NREP; ++n) {
        const int col = n0 + wc * WN + n * 16 + fr;
        float v = acc[m][n][r];
        if constexpr (EPI == 2 || EPI == 3 || EPI == 6) v += bias[col];
        if constexpr (EPI == 3) v += aux[(size_t)(row / N_) * N + col];
        if constexpr (EPI == 4 || EPI == 7) v += aux[(size_t)row * N + col];
        if constexpr (EPI == 5) v = 0.5f * v * (1.0f + erff(v * 0.70710678118654752f));
        if constexpr (EPI == 6) {
          int c2 = (col < D_) ? col : col - D_;
          int hh = c2 >> 6, dd = c2 & 63;
          u16* dst = (u16*)out2 + ((col < D_) ? 0 : KVOFF);
          dst[(((size_t)bb6 * H_ + hh) * KL_ + jj6) * DH_ + dd] = f2bf(v);
        } else if constexpr (EPI == 8) {
          if (col < D_) {
            reinterpret_cast<u16*>(out)[(size_t)row * D_ + col] = f2bf(v);
          } else {
            int cc = col - D_;
            int bb = row >> 4, jj = N_ + (row & 15);
            int c2 = (cc < D_) ? cc : cc - D_;
            int hh = c2 >> 6, dd = c2 & 63;
            u16* dst = (u16*)out2 + ((cc < D_) ? 0 : KVOFF);
            dst[(((size_t)bb * H_ + hh) * KL_ + jj) * DH_ + dd] = f2bf(v);
          }
        } else if constexpr (EPI == 7) {
          reinterpret_cast<float*>(out)[(size_t)row * N + col] = v;
          reinterpret_cast<u16*>(out2)[(size_t)row * N + col] = f2bf(v);
        } else if constexpr (EPI == 2 || EPI == 4) {
          reinterpret_cast<float*>(out)[(size_t)row * N + col] = v;
        } else {
          reinterpret_cast<u16*>(out)[(size_t)row * N + col] = f2bf(v);
        }
      }
    }
  }
}

// ---------------- fused per-layer weight prep (ada batched pre-loop) ----------------
__global__ __launch_bounds__(256) void k_prep(
    const float* __restrict__ kvw, const float* __restrict__ g, const float* __restrict__ bvec,
    u16* __restrict__ kvf, u16* __restrict__ kvwb, float* __restrict__ kvb,
    const float* __restrict__ qw,  u16* __restrict__ dqw,
    const float* __restrict__ ow,  u16* __restrict__ dow,
    const float* __restrict__ f1w, u16* __restrict__ df1,
    const float* __restrict__ f2w, u16* __restrict__ df2)
{
  __shared__ float sl[4];
  const int bid = blockIdx.x, tid = threadIdx.x;
  if (bid < 2048) {
    int o = bid;
    float4 w = reinterpret_cast<const float4*>(kvw + (size_t)o * D_)[tid];
    float4 gg = reinterpret_cast<const float4*>(g)[tid];
    float4 bv = reinterpret_cast<const float4*>(bvec)[tid];
    ushort4 f;
    f.x = f2bf(w.x * gg.x); f.y = f2bf(w.y * gg.y); f.z = f2bf(w.z * gg.z); f.w = f2bf(w.w * gg.w);
    reinterpret_cast<ushort4*>(kvf + (size_t)o * D_)[tid] = f;
    ushort4 f2;
    f2.x = f2bf(w.x); f2.y = f2bf(w.y); f2.z = f2bf(w.z); f2.w = f2bf(w.w);
    reinterpret_cast<ushort4*>(kvwb + (size_t)o * D_)[tid] = f2;
    float s = w.x * bv.x + w.y * bv.y + w.z * bv.z + w.w * bv.w;
    for (int off = 32; off; off >>= 1) s += __shfl_down(s, off);
    if ((tid & 63) == 0) sl[tid >> 6] = s;
    __syncthreads();
    if (tid == 0) kvb[o] = sl[0] + sl[1] + sl[2] + sl[3];
  } else {
    int id = bid - 2048;
    const float* src; u16* dst; int off;
    if      (id < 1024)  { src = qw;  dst = dqw; off = id; }
    else if (id < 2048)  { src = ow;  dst = dow; off = id - 1024; }
    else if (id < 6144)  { src = f1w; dst = df1; off = id - 2048; }
    else                 { src = f2w; dst = df2; off = id - 6144; }
    size_t base = (size_t)off * 1024 + (size_t)tid * 4;
    float4 v = *reinterpret_cast<const float4*>(src + base);
    ushort4 u; u.x = f2bf(v.x); u.y = f2bf(v.y); u.z = f2bf(v.z); u.w = f2bf(v.w);
    *reinterpret_cast<ushort4*>(dst + base) = u;
  }
}

// ---------------- timestep embedding MLP ----------------
__global__ void k_temb1(const float* __restrict__ tsf, const float* __restrict__ w1,
                        const float* __restrict__ b1, float* __restrict__ h1tT){
  int o = blockIdx.x, b = threadIdx.x;  // 1024 x 64
  float t = tsf[b];
  float acc = b1[o];
  const float c = -9.210340371976184f / 160.0f;  // -ln(10000)/160
  for (int j = 0; j < 160; ++j) {
    float arg = t * expf(c * (float)j);
    acc += w1[(size_t)o * T_ + j] * cosf(arg) + w1[(size_t)o * T_ + 160 + j] * sinf(arg);
  }
  float s = acc / (1.0f + expf(-acc));
  h1tT[(size_t)o * B_ + b] = s;
}

__global__ void k_temb2(const float* __restrict__ h1tT, const float* __restrict__ w2,
                        const float* __restrict__ b2, float* __restrict__ temb){
  int o = blockIdx.x, b = threadIdx.x;  // 1024 x 64
  float acc = b2[o];
  for (int d = 0; d < D_; ++d) acc += h1tT[(size_t)d * B_ + b] * w2[(size_t)o * D_ + d];
  temb[(size_t)b * D_ + o] = acc;
}

__global__ void k_silu(const float* __restrict__ in, u16* __restrict__ outb, int n){
  int i = blockIdx.x * blockDim.x + threadIdx.x;
  if (i < n) { float x = in[i]; outb[i] = f2bf(x / (1.0f + expf(-x))); }
}

__global__ void k_init_lat(const float* __restrict__ latents, float* __restrict__ lat){
  int i = blockIdx.x * blockDim.x + threadIdx.x;
  if (i < BQ_ * D_) lat[i] = latents[i & (Q_ * D_ - 1)];
}

// ---------------- row LayerNorm (no affine), bf16 -> bf16 ----------------
__global__ __launch_bounds__(256) void k_rownorm(const u16* __restrict__ xp, u16* __restrict__ outb){
  __shared__ float s1[4], s2[4];
  size_t row = blockIdx.x;
  int tid = threadIdx.x;
  ushort4 u = reinterpret_cast<const ushort4*>(xp + row * D_)[tid];
  float v0 = bf2f(u.x), v1 = bf2f(u.y), v2 = bf2f(u.z), v3 = bf2f(u.w);
  float s = v0 + v1 + v2 + v3;
  float q = v0 * v0 + v1 * v1 + v2 * v2 + v3 * v3;
  for (int off = 32; off; off >>= 1) { s += __shfl_down(s, off); q += __shfl_down(q, off); }
  if ((tid & 63) == 0) { s1[tid >> 6] = s; s2[tid >> 6] = q; }
  __syncthreads();
  float S = s1[0] + s1[1] + s1[2] + s1[3], Qv = s2[0] + s2[1] + s2[2] + s2[3];
  float mean = S * (1.f / D_);
  float rs = rsqrtf(Qv * (1.f / D_) - mean * mean + 1e-5f);
  ushort4 o;
  o.x = f2bf((v0 - mean) * rs); o.y = f2bf((v1 - mean) * rs);
  o.z = f2bf((v2 - mean) * rs); o.w = f2bf((v3 - mean) * rs);
  reinterpret_cast<ushort4*>(outb + row * D_)[tid] = o;
}

// ---------------- LayerNorm + AdaLN modulation, fp32 -> bf16 ----------------
__global__ __launch_bounds__(256) void k_lnmod(const float* __restrict__ in, const float* __restrict__ g,
                                               const float* __restrict__ bb, const float* __restrict__ modp,
                                               int mstride, u16* __restrict__ outb){
  __shared__ float s1[4], s2[4];
  int row = blockIdx.x, tid = threadIdx.x;
  int b = row >> 4;
  float4 v = reinterpret_cast<const float4*>(in + (size_t)row * D_)[tid];
  float s = v.x + v.y + v.z + v.w;
  float q = v.x * v.x + v.y * v.y + v.z * v.z + v.w * v.w;
  for (int off = 32; off; off >>= 1) { s += __shfl_down(s, off); q += __shfl_down(q, off); }
  if ((tid & 63) == 0) { s1[tid >> 6] = s; s2[tid >> 6] = q; }
  __syncthreads();
  float S = s1[0] + s1[1] + s1[2] + s1[3], Qv = s2[0] + s2[1] + s2[2] + s2[3];
  float mean = S * (1.f / D_);
  float rs = rsqrtf(Qv * (1.f / D_) - mean * mean + 1e-5f);
  float4 gg = reinterpret_cast<const float4*>(g)[tid];
  float4 bv = reinterpret_cast<const float4*>(bb)[tid];
  const float* mrow = modp + (size_t)b * mstride;
  float4 sh = reinterpret_cast<const float4*>(mrow)[tid];
  float4 scv = reinterpret_cast<const float4*>(mrow + D_)[tid];
  ushort4 o;
  o.x = f2bf(((v.x - mean) * rs * gg.x + bv.x) * (1.f + scv.x) + sh.x);
  o.y = f2bf(((v.y - mean) * rs * gg.y + bv.y) * (1.f + scv.y) + sh.y);
  o.z = f2bf(((v.z - mean) * rs * gg.z + bv.z) * (1.f + scv.z) + sh.z);
  o.w = f2bf(((v.w - mean) * rs * gg.w + bv.w) * (1.f + scv.w) + sh.w);
  reinterpret_cast<ushort4*>(outb + (size_t)row * D_)[tid] = o;
}

// ---------------- final LayerNorm (affine), fp32 -> fp32 out ----------------
__global__ __launch_bounds__(256) void k_lnfinal(const float* __restrict__ in, const float* __restrict__ g,
                                                 const float* __restrict__ bb, float* __restrict__ outf){
  __shared__ float s1[4], s2[4];
  int row = blockIdx.x, tid = threadIdx.x;
  float4 v = reinterpret_cast<const float4*>(in + (size_t)row * O_)[tid];
  float s = v.x + v.y + v.z + v.w;
  float q = v.x * v.x + v.y * v.y + v.z * v.z + v.w * v.w;
  for (int off = 32; off; off >>= 1) { s += __shfl_down(s, off); q += __shfl_down(q, off); }
  if ((tid & 63) == 0) { s1[tid >> 6] = s; s2[tid >> 6] = q; }
  __syncthreads();
  float S = s1[0] + s1[1] + s1[2] + s1[3], Qv = s2[0] + s2[1] + s2[2] + s2[3];
  float mean = S * (1.f / O_);
  float rs = rsqrtf(Qv * (1.f / O_) - mean * mean + 1e-5f);
  float4 gg = reinterpret_cast<const float4*>(g)[tid];
  float4 bv = reinterpret_cast<const float4*>(bb)[tid];
  float4 o;
  o.x = (v.x - mean) * rs * gg.x + bv.x;
  o.y = (v.y - mean) * rs * gg.y + bv.y;
  o.z = (v.z - mean) * rs * gg.z + bv.z;
  o.w = (v.w - mean) * rs * gg.w + bv.w;
  reinterpret_cast<float4*>(outf + (size_t)row * O_)[tid] = o;
}

// ---------------- attention v3: head-major K/V, LDS-tiled QK^T AND PV ----------------
__global__ __launch_bounds__(256) void k_attn2(const u16* __restrict__ qb,
                                               const u16* __restrict__ kb,
                                               const u16* __restrict__ vb,
                                               u16* __restrict__ ob){
  __shared__ float qs[Q_][DH_ + 4];
  __shared__ u16   ks[128][DH_ + 4];   // K tile, reused as V tile in PV phase
  __shared__ float sc[Q_][600];
  __shared__ float rsum[Q_];
  const int bh  = blockIdx.x;           // b*16 + h
  const int b   = bh >> 4, h = bh & 15;
  const int tid = threadIdx.x;
  {
    int qi = tid >> 4, d4 = (tid & 15) << 2;
    ushort4 u = *reinterpret_cast<const ushort4*>(qb + (size_t)(b * Q_ + qi) * D_ + h * DH_ + d4);
    qs[qi][d4 + 0] = 0.125f * bf2f(u.x);   // sc*sc = 1/sqrt(DH) folded into Q
    qs[qi][d4 + 1] = 0.125f * bf2f(u.y);
    qs[qi][d4 + 2] = 0.125f * bf2f(u.z);
    qs[qi][d4 + 3] = 0.125f * bf2f(u.w);
  }
  const u16* kbh = kb + (size_t)bh * KL_ * DH_;
  const u16* vbh = vb + (size_t)bh * KL_ * DH_;
  for (int j0 = 0; j0 < KL_; j0 += 128) {
    int rows = KL_ - j0; if (rows > 128) rows = 128;
    __syncthreads();
    for (int idx = tid; idx < rows * 16; idx += 256) {
      int r = idx >> 4, c4 = (idx & 15) << 2;
      *reinterpret_cast<ushort4*>(&ks[r][c4]) =
          *reinterpret_cast<const ushort4*>(kbh + (size_t)(j0 + r) * DH_ + c4);
    }
    __syncthreads();
    for (int e = tid; e < Q_ * 128; e += 256) {
      int jj = e & 127, qi = e >> 7;
      if (jj < rows) {
        float s = 0.f;
        #pragma unroll
        for (int d = 0; d < DH_; d += 4) {
          ushort4 u = *reinterpret_cast<const ushort4*>(&ks[jj][d]);
          s += qs[qi][d] * bf2f(u.x) + qs[qi][d + 1] * bf2f(u.y)
             + qs[qi][d + 2] * bf2f(u.z) + qs[qi][d + 3] * bf2f(u.w);
        }
        sc[qi][j0 + jj] = s;
      }
    }
  }
  __syncthreads();
  {
    int g = tid >> 4, l = tid & 15;
    float mx = -1e30f;
    for (int j = l; j < KL_; j += 16) mx = fmaxf(mx, sc[g][j]);
    for (int m = 1; m < 16; m <<= 1) mx = fmaxf(mx, __shfl_xor(mx, m));
    float sum = 0.f;
    for (int j = l; j < KL_; j += 16) { float e = expf(sc[g][j] - mx); sc[g][j] = e; sum += e; }
    for (int m = 1; m < 16; m <<= 1) sum += __shfl_xor(sum, m);
    if (l == 0) rsum[g] = sum;
  }
  // PV phase: stage V tiles in LDS (reuse ks), accumulate
  {
    int d = tid & 63, q0 = tid >> 6;
    float acc[4] = {0.f, 0.f, 0.f, 0.f};
    for (int j0 = 0; j0 < KL_; j0 += 128) {
      int rows = KL_ - j0; if (rows > 128) rows = 128;
      __syncthreads();
      for (int idx = tid; idx < rows * 16; idx += 256) {
        int r = idx >> 4, c4 = (idx & 15) << 2;
        *reinterpret_cast<ushort4*>(&ks[r][c4]) =
            *reinterpret_cast<const ushort4*>(vbh + (size_t)(j0 + r) * DH_ + c4);
      }
      __syncthreads();
      for (int jj = 0; jj < rows; ++jj) {
        float vj = bf2f(ks[jj][d]);
        #pragma unroll
        for (int t = 0; t < 4; ++t) acc[t] += sc[q0 + t * 4][j0 + jj] * vj;
      }
    }
    #pragma unroll
    for (int t = 0; t < 4; ++t) {
      int qi = q0 + t * 4;
      ob[(size_t)(b * Q_ + qi) * D_ + h * DH_ + d] = f2bf(acc[t] / rsum[qi]);
    }
  }
}

// ---------------- host ----------------
static void conv_launch(const float* src, u16* dst, size_t n, hipStream_t s){
  long long n4 = (long long)(n >> 2);
  int blocks = (int)((n4 + 255) / 256);
  if (blocks > 4096) blocks = 4096;
  k_f2b<<<blocks, 256, 0, s>>>(src, dst, n4);
}

template<int EPI, int BM, int BN>
static void gemm(const u16* X, const u16* W, const float* bias, const float* aux,
                 void* out, void* out2, int M, int N, int K, hipStream_t s){
  dim3 g(N / BN, (M + BM - 1) / BM);
  k_gemm<EPI, BM, BN><<<g, 256, 0, s>>>(X, W, bias, aux, out, out2, M, N, K);
}

extern "C" void kernel_launch(void* const* d_in, const int* in_sizes, int n_in,
                              void* d_out, int out_size, void* d_ws, size_t ws_size,
                              hipStream_t stream)
{
  const float* x         = (const float*)d_in[0];
  const int*   tsp       = (const int*)  d_in[1];
  const float* latents   = (const float*)d_in[2];
  const float* proj_in_w = (const float*)d_in[3];
  const float* proj_in_b = (const float*)d_in[4];
  const float* time_w1   = (const float*)d_in[5];
  const float* time_b1   = (const float*)d_in[6];
  const float* time_w2   = (const float*)d_in[7];
  const float* time_b2   = (const float*)d_in[8];
  const float* ln1_g     = (const float*)d_in[9];
  const float* ln1_b     = (const float*)d_in[10];
  const float* ln2_g     = (const float*)d_in[11];
  const float* ln2_b     = (const float*)d_in[12];
  const float* q_w       = (const float*)d_in[13];
  const float* kv_w      = (const float*)d_in[14];
  const float* out_w     = (const float*)d_in[15];
  const float* ffln_g    = (const float*)d_in[16];
  const float* ffln_b    = (const float*)d_in[17];
  const float* ff_w1     = (const float*)d_in[18];
  const float* ff_w2     = (const float*)d_in[19];
  const float* ada_w     = (const float*)d_in[20];
  const float* ada_b     = (const float*)d_in[21];
  const float* proj_out_w= (const float*)d_in[22];
  const float* proj_out_b= (const float*)d_in[23];
  const float* nout_g    = (const float*)d_in[24];
  const float* nout_b    = (const float*)d_in[25];

  char* Wp = (char*)d_ws;
  size_t off = 0;
  auto alloc = [&](size_t bytes) -> void* {
    void* p = Wp + off;
    off = (off + bytes + 255) & ~(size_t)255;
    return p;
  };

  float* tsf   = (float*)alloc((size_t)B_ * 4);
  float* temb  = (float*)alloc((size_t)B_ * D_ * 4);
  float* h1tT  = (float*)alloc((size_t)D_ * B_ * 4);
  u16*   stemb = (u16*)  alloc((size_t)B_ * D_ * 2);
  float* modb8 = (float*)alloc((size_t)B_ * L_ * 4 * D_ * 4);   // [64][32768] all layers
  float* kvb   = (float*)alloc((size_t)2 * D_ * 4);
  float* lat   = (float*)alloc((size_t)BQ_ * D_ * 4);
  u16*   lt    = (u16*)  alloc((size_t)BQ_ * D_ * 2);
  u16*   qb    = (u16*)  alloc((size_t)BQ_ * D_ * 2);
  u16*   ob    = (u16*)  alloc((size_t)BQ_ * D_ * 2);
  u16*   hb    = (u16*)  alloc((size_t)BQ_ * D_ * 2);
  u16*   h1b   = (u16*)  alloc((size_t)BQ_ * FF_ * 2);
  u16*   latb  = (u16*)  alloc((size_t)BQ_ * D_ * 2);
  float* tmpf  = (float*)alloc((size_t)BQ_ * D_ * 4);
  u16*   wpin  = (u16*)  alloc((size_t)D_ * E_ * 2);
  u16*   wada8 = (u16*)  alloc((size_t)L_ * 4 * D_ * D_ * 2);   // all layers, bf16
  u16*   wpout = (u16*)  alloc((size_t)O_ * D_ * 2);
  u16*   kvf   = (u16*)  alloc((size_t)2 * D_ * D_ * 2);
  u16*   wqkv  = (u16*)  alloc((size_t)3 * D_ * D_ * 2);   // [q_w ; kv_w] stacked bf16
  u16*   wouti = (u16*)  alloc((size_t)D_ * D_ * 2);
  u16*   wff1i = (u16*)  alloc((size_t)FF_ * D_ * 2);
  u16*   wff2i = (u16*)  alloc((size_t)D_ * FF_ * 2);
  u16*   nxp   = (u16*)  alloc((size_t)MX_ * D_ * 2);
  u16*   kvwb  = wqkv + (size_t)D_ * D_;                   // rows 1024..3071 of wqkv
  // big region: prologue [xb | xpb], layer loop [kbuf | vbuf] (disjoint lifetimes)
  size_t xb_sz  = (size_t)B_ * N_ * E_ * 2;
  size_t xpb_sz = (size_t)MX_ * D_ * 2;
  size_t kv_sz  = (size_t)B_ * H_ * KL_ * DH_ * 2;
  size_t big_sz = (xb_sz + xpb_sz > 2 * kv_sz) ? (xb_sz + xpb_sz) : 2 * kv_sz;
  char* big = (char*)alloc(big_sz);
  u16* xb   = (u16*)big;
  u16* xpb  = (u16*)(big + xb_sz);
  u16* kbuf = (u16*)big;
  u16* vbuf = (u16*)(big + kv_sz);   // == kbuf + KVOFF elements

  // ---- weight / input conversions (layer-invariant) ----
  conv_launch(x,          xb,    (size_t)B_ * N_ * E_, stream);
  conv_launch(proj_in_w,  wpin,  (size_t)D_ * E_,      stream);
  conv_launch(proj_out_w, wpout, (size_t)O_ * D_,      stream);
  conv_launch(ada_w,      wada8, (size_t)L_ * 4 * D_ * D_, stream);

  // ---- timestep embedding ----
  k_tsnorm<<<1, B_, 0, stream>>>(tsp, tsf);
  k_temb1<<<D_, B_, 0, stream>>>(tsf, time_w1, time_b1, h1tT);
  k_temb2<<<D_, B_, 0, stream>>>(h1tT, time_w2, time_b2, temb);
  k_silu<<<(B_ * D_ + 255) / 256, 256, 0, stream>>>(temb, stemb, B_ * D_);

  // ---- AdaLN mod for ALL layers in one GEMM: [64, 32768] ----
  gemm<2, 64, 64>(stemb, wada8, ada_b, nullptr, modb8, nullptr, B_, L_ * 4 * D_, D_, stream);

  // ---- proj_in + temb ----
  gemm<3, 128, 128>(xb, wpin, proj_in_b, temb, xpb, nullptr, MX_, D_, E_, stream);
  k_rownorm<<<MX_, 256, 0, stream>>>(xpb, nxp);
  k_init_lat<<<(BQ_ * D_) / 256, 256, 0, stream>>>(latents, lat);

  const int MSTR = L_ * 4 * D_;   // 32768: per-batch row stride in modb8
  for (int i = 0; i < L_; ++i) {
    // fused per-layer weight prep (fold + 4 conversions)
    k_prep<<<12288, 256, 0, stream>>>(
        kv_w + (size_t)i * 2 * D_ * D_, ln1_g + i * D_, ln1_b + i * D_,
        kvf, kvwb, kvb,
        q_w   + (size_t)i * D_ * D_,  wqkv,
        out_w + (size_t)i * D_ * D_,  wouti,
        ff_w1 + (size_t)i * FF_ * D_, wff1i,
        ff_w2 + (size_t)i * D_ * FF_, wff2i);

    // kv over x tokens (dominant GEMM) -> head-major K/V, LN1 folded into weights
    gemm<6, 128, 128>(nxp, kvf, kvb, nullptr, nullptr, kbuf, MX_, 2 * D_, D_, stream);
    // modulated latents
    k_lnmod<<<BQ_, 256, 0, stream>>>(lat, ln2_g + i * D_, ln2_b + i * D_,
                                     modb8 + (size_t)i * 4 * D_, MSTR, lt);
    // merged q-proj + latent-kv: N = 3072
    gemm<8, 64, 64>(lt, wqkv, nullptr, nullptr, qb, kbuf, BQ_, 3 * D_, D_, stream);
    k_attn2<<<B_ * H_, 256, 0, stream>>>(qb, kbuf, vbuf, ob);
    gemm<4, 64, 64>(ob, wouti, nullptr, lat, lat, nullptr, BQ_, D_, D_, stream);
    // FFN
    k_lnmod<<<BQ_, 256, 0, stream>>>(lat, ffln_g + i * D_, ffln_b + i * D_,
                                     modb8 + (size_t)i * 4 * D_ + 2 * D_, MSTR, hb);
    gemm<5, 64, 64>(hb, wff1i, nullptr, nullptr, h1b, nullptr, BQ_, FF_, D_, stream);
    if (i < L_ - 1)
      gemm<4, 64, 64>(h1b, wff2i, nullptr, lat, lat, nullptr, BQ_, D_, FF_, stream);
    else  // last layer: also emit bf16 copy for the output projection
      gemm<7, 64, 64>(h1b, wff2i, nullptr, lat, lat, latb, BQ_, D_, FF_, stream);
  }

  // ---- output projection + final LN (fp32 output) ----
  gemm<2, 64, 64>(latb, wpout, proj_out_b, nullptr, tmpf, nullptr, BQ_, O_, D_, stream);
  k_lnfinal<<<BQ_, 256, 0, stream>>>(tmpf, nout_g, nout_b, (float*)d_out);
}

// Round 27
// 3649.402 us; speedup vs baseline: 1.0129x; 1.0038x over previous
//
#include <hip/hip_runtime.h>
#include <hip/hip_bf16.h>
#include <math.h>

// ---------------- problem dims ----------------
#define B_  64
#define N_  577
#define E_  768
#define D_  1024
#define L_  8
#define Q_  16
#define H_  16
#define DH_ 64
#define T_  320
#define FF_ 4096
#define O_  1024
#define MX_ (B_*N_)    // 36928 rows of x / xp
#define KL_ (N_+Q_)    // 593 kv rows per batch
#define BQ_ (B_*Q_)    // 1024 latent rows
#define KVOFF ((size_t)B_*H_*KL_*DH_)   // u16 elements between kbuf and vbuf

typedef unsigned short u16;
typedef __bf16 v8bf __attribute__((ext_vector_type(8)));
typedef float  v4f  __attribute__((ext_vector_type(4)));

__device__ __forceinline__ float bf2f(u16 u){
  union { float f; unsigned int i; } v; v.i = ((unsigned int)u) << 16; return v.f;
}
__device__ __forceinline__ u16 f2bf(float f){
  union { float f; unsigned int i; } v; v.f = f;
  unsigned int x = v.i;
  return (u16)((x + 0x7fffu + ((x >> 16) & 1u)) >> 16);  // RNE
}

// async global->LDS, 16B per lane; LDS dest = wave-uniform base + lane*16
__device__ __forceinline__ void gld16(const u16* g, u16* l){
  __builtin_amdgcn_global_load_lds(
      (const __attribute__((address_space(1))) void*)g,
      (__attribute__((address_space(3))) void*)l, 16, 0, 0);
}

// ---------------- timestep decode: int32 or int64 ----------------
__global__ void k_tsnorm(const int* __restrict__ raw, float* __restrict__ tsf){
  __shared__ int nz;
  int tid = threadIdx.x;  // 64
  if (tid == 0) nz = 0;
  __syncthreads();
  if (tid < 32 && raw[2 * tid + 1] != 0) atomicOr(&nz, 1);
  __syncthreads();
  int t = (nz == 0) ? raw[2 * tid] : raw[tid];
  tsf[tid] = (float)t;
}

// ---------------- fp32 -> bf16 conversion (vectorized) ----------------
__global__ void k_f2b(const float* __restrict__ src, u16* __restrict__ dst, long long n4){
  long long i = (long long)blockIdx.x * blockDim.x + threadIdx.x;
  long long stride = (long long)gridDim.x * blockDim.x;
  for (; i < n4; i += stride){
    float4 f = reinterpret_cast<const float4*>(src)[i];
    ushort4 u; u.x = f2bf(f.x); u.y = f2bf(f.y); u.z = f2bf(f.z); u.w = f2bf(f.w);
    reinterpret_cast<ushort4*>(dst)[i] = u;
  }
}

// ---------------- MFMA GEMM: C[M,N] = X[M,K] * W[N,K]^T (+epilogue) ----------------
// EPI: 0 bf16 | 2 +bias f32 | 3 +bias+temb bf16 | 4 +residual f32
//      5 GELU bf16 | 6 kv(x rows)+bias -> head-major K/V (out2=K base, V=+KVOFF)
//      7 +residual f32 AND bf16 copy (out2)
//      8 merged q + latent-kv: col<D -> qb (out), col>=D -> head-major K/V (out2)
//      9 split-K: fp32 atomicAdd into out (residual accumulates in place)
// Ring-3 triple buffer (depth-2 pipeline) for BOTH tile paths (48KB LDS):
//   BM=128/BN=128/BK=32 (kv, proj_in) and BM=64/BN=64/BK=64 (small GEMMs, +setprio).
//   LPW == 4 for both -> vmcnt(8)/(4)/(0) ladder identical.
// K = chunk length (per blockIdx.z), Ks = row stride (full K). Non-split: K == Ks.
template<int EPI, int BM, int BN>
__global__ __launch_bounds__(256) void k_gemm(
    const u16* __restrict__ X, const u16* __restrict__ Wm,
    const float* __restrict__ bias, const float* __restrict__ aux,
    void* __restrict__ out, void* __restrict__ out2, int M, int N, int K, int Ks)
{
  constexpr int BK   = (BM == 128) ? 32 : 64;
  constexpr int WM   = BM / 2, WN = BN / 2;
  constexpr int MREP = WM / 16, NREP = WN / 16;
  constexpr int RPC  = 512 / BK;
  constexpr int NCHA = BM / RPC;
  constexpr int NCHB = BN / RPC;
  constexpr int NCH  = NCHA + NCHB;
  constexpr int LPW  = NCH / 4;
  static_assert(LPW == 4, "vmcnt ladder assumes LPW==4");
  __shared__ u16 As[3 * BM * BK];
  __shared__ u16 Bs[3 * BN * BK];
  if constexpr (EPI == 9) {           // K-chunk base for this z-slice
    X  += (size_t)blockIdx.z * K;
    Wm += (size_t)blockIdx.z * K;
  }
  const int tid  = threadIdx.x;
  const int lane = tid & 63;
  const int wid  = tid >> 6;
  const int wr   = wid >> 1, wc = wid & 1;
  const int m0   = blockIdx.y * BM, n0 = blockIdx.x * BN;
  const int fr   = lane & 15;
  const int js   = lane >> 4;
  const int fsw  = (fr >> 1) & ((BK == 32) ? 3 : 7);

  v4f zero = {0.f, 0.f, 0.f, 0.f};
  v4f acc[MREP][NREP];
  #pragma unroll
  for (int m = 0; m < MREP; ++m)
    #pragma unroll
    for (int n = 0; n < NREP; ++n) acc[m][n] = zero;

  int  aofs[LPW]; int loff[LPW]; bool isAv[LPW];
  #pragma unroll
  for (int p = 0; p < LPW; ++p) {
    const int ch = wid * LPW + p;
    const bool isA = (ch < NCHA);
    const int cb = isA ? ch : ch - NCHA;
    int grow, gc;
    if constexpr (BK == 32) {
      grow = cb * 16 + (lane >> 2);
      const int fst = (lane >> 3) & 3;
      gc = (((lane & 3) ^ fst) << 3);
    } else {
      grow = cb * 8 + (lane >> 3);
      const int fst = (cb * 4 + (lane >> 4)) & 7;
      gc = (((lane & 7) ^ fst) << 3);
    }
    isAv[p] = isA; loff[p] = cb * 512;
    if (isA) { int ar = m0 + grow; if (ar > M - 1) ar = M - 1; aofs[p] = ar * Ks + gc; }
    else     { int br = n0 + grow;                              aofs[p] = br * Ks + gc; }
  }

  auto stage = [&](int buf, int k0){
    const u16* Xk = X + k0;
    const u16* Wk = Wm + k0;
    #pragma unroll
    for (int p = 0; p < LPW; ++p) {
      if (isAv[p]) gld16(Xk + aofs[p], &As[buf * BM * BK + loff[p]]);
      else         gld16(Wk + aofs[p], &Bs[buf * BN * BK + loff[p]]);
    }
  };

  auto compute = [&](const u16* Ab, const u16* Bb){
    if constexpr (BM == 64) __builtin_amdgcn_s_setprio(1);
    #pragma unroll
    for (int kk = 0; kk < BK / 32; ++kk) {
      const int ps = (((kk * 4 + js) ^ fsw) << 3);
      v8bf a[MREP], b[NREP];
      #pragma unroll
      for (int m = 0; m < MREP; ++m)
        a[m] = *reinterpret_cast<const v8bf*>(Ab + (wr * WM + m * 16 + fr) * BK + ps);
      #pragma unroll
      for (int n = 0; n < NREP; ++n)
        b[n] = *reinterpret_cast<const v8bf*>(Bb + (wc * WN + n * 16 + fr) * BK + ps);
      #pragma unroll
      for (int m = 0; m < MREP; ++m)
        #pragma unroll
        for (int n = 0; n < NREP; ++n)
          acc[m][n] = __builtin_amdgcn_mfma_f32_16x16x32_bf16(a[m], b[n], acc[m][n], 0, 0, 0);
    }
    if constexpr (BM == 64) __builtin_amdgcn_s_setprio(0);
  };

  const int nt = K / BK;   // >= 16 at every call site (>= ring depth)
  stage(0, 0);
  stage(1, BK);
  int bi = 0;
  for (int t = 0; t < nt; ++t) {
    if (t + 2 < nt) {
      int sb = bi + 2; if (sb >= 3) sb -= 3;
      stage(sb, (t + 2) * BK);
      asm volatile("s_waitcnt vmcnt(8)" ::: "memory");   // tile t's 4 loads done
    } else if (t + 1 < nt) {
      asm volatile("s_waitcnt vmcnt(4)" ::: "memory");
    } else {
      asm volatile("s_waitcnt vmcnt(0)" ::: "memory");
    }
    __builtin_amdgcn_s_barrier();      // all waves' tile-t loads landed
    compute(&As[bi * BM * BK], &Bs[bi * BN * BK]);
    __builtin_amdgcn_s_barrier();      // buf[t] reads done before stage(t+3) next iter
    ++bi; if (bi == 3) bi = 0;
  }

  const int rq = (lane >> 4) << 2;
  #pragma unroll
  for (int m = 0; m < MREP; ++m) {
    #pragma unroll
    for (int r = 0; r < 4; ++r) {
      const int row = m0 + wr * WM + m * 16 + rq + r;
      if (row >= M) continue;
      int bb6 = 0, jj6 = 0;
      if constexpr (EPI == 6) { bb6 = row / N_; jj6 = row - bb6 * N_; }
      #pragma unroll
      for (int n = 0; n < NREP; ++n) {
        const int col = n0 + wc * WN + n * 16 + fr;
        float v = acc[m][n][r];
        if constexpr (EPI == 2 || EPI == 3 || EPI == 6) v += bias[col];
        if constexpr (EPI == 3) v += aux[(size_t)(row / N_) * N + col];
        if constexpr (EPI == 4 || EPI == 7) v += aux[(size_t)row * N + col];
        if constexpr (EPI == 5) v = 0.5f * v * (1.0f + erff(v * 0.70710678118654752f));
        if constexpr (EPI == 6) {
          int c2 = (col < D_) ? col : col - D_;
          int hh = c2 >> 6, dd = c2 & 63;
          u16* dst = (u16*)out2 + ((col < D_) ? 0 : KVOFF);
          dst[(((size_t)bb6 * H_ + hh) * KL_ + jj6) * DH_ + dd] = f2bf(v);
        } else if constexpr (EPI == 8) {
          if (col < D_) {
            reinterpret_cast<u16*>(out)[(size_t)row * D_ + col] = f2bf(v);
          } else {
            int cc = col - D_;
            int bb = row >> 4, jj = N_ + (row & 15);
            int c2 = (cc < D_) ? cc : cc - D_;
            int hh = c2 >> 6, dd = c2 & 63;
            u16* dst = (u16*)out2 + ((cc < D_) ? 0 : KVOFF);
            dst[(((size_t)bb * H_ + hh) * KL_ + jj) * DH_ + dd] = f2bf(v);
          }
        } else if constexpr (EPI == 9) {
          atomicAdd(reinterpret_cast<float*>(out) + (size_t)row * N + col, v);
        } else if constexpr (EPI == 7) {
          reinterpret_cast<float*>(out)[(size_t)row * N + col] = v;
          reinterpret_cast<u16*>(out2)[(size_t)row * N + col] = f2bf(v);
        } else if constexpr (EPI == 2 || EPI == 4) {
          reinterpret_cast<float*>(out)[(size_t)row * N + col] = v;
        } else {
          reinterpret_cast<u16*>(out)[(size_t)row * N + col] = f2bf(v);
        }
      }
    }
  }
}

// ---------------- fused per-layer weight prep (ada batched pre-loop) ----------------
__global__ __launch_bounds__(256) void k_prep(
    const float* __restrict__ kvw, const float* __restrict__ g, const float* __restrict__ bvec,
    u16* __restrict__ kvf, u16* __restrict__ kvwb, float* __restrict__ kvb,
    const float* __restrict__ qw,  u16* __restrict__ dqw,
    const float* __restrict__ ow,  u16* __restrict__ dow,
    const float* __restrict__ f1w, u16* __restrict__ df1,
    const float* __restrict__ f2w, u16* __restrict__ df2)
{
  __shared__ float sl[4];
  const int bid = blockIdx.x, tid = threadIdx.x;
  if (bid < 2048) {
    int o = bid;
    float4 w = reinterpret_cast<const float4*>(kvw + (size_t)o * D_)[tid];
    float4 gg = reinterpret_cast<const float4*>(g)[tid];
    float4 bv = reinterpret_cast<const float4*>(bvec)[tid];
    ushort4 f;
    f.x = f2bf(w.x * gg.x); f.y = f2bf(w.y * gg.y); f.z = f2bf(w.z * gg.z); f.w = f2bf(w.w * gg.w);
    reinterpret_cast<ushort4*>(kvf + (size_t)o * D_)[tid] = f;
    ushort4 f2;
    f2.x = f2bf(w.x); f2.y = f2bf(w.y); f2.z = f2bf(w.z); f2.w = f2bf(w.w);
    reinterpret_cast<ushort4*>(kvwb + (size_t)o * D_)[tid] = f2;
    float s = w.x * bv.x + w.y * bv.y + w.z * bv.z + w.w * bv.w;
    for (int off = 32; off; off >>= 1) s += __shfl_down(s, off);
    if ((tid & 63) == 0) sl[tid >> 6] = s;
    __syncthreads();
    if (tid == 0) kvb[o] = sl[0] + sl[1] + sl[2] + sl[3];
  } else {
    int id = bid - 2048;
    const float* src; u16* dst; int off;
    if      (id < 1024)  { src = qw;  dst = dqw; off = id; }
    else if (id < 2048)  { src = ow;  dst = dow; off = id - 1024; }
    else if (id < 6144)  { src = f1w; dst = df1; off = id - 2048; }
    else                 { src = f2w; dst = df2; off = id - 6144; }
    size_t base = (size_t)off * 1024 + (size_t)tid * 4;
    float4 v = *reinterpret_cast<const float4*>(src + base);
    ushort4 u; u.x = f2bf(v.x); u.y = f2bf(v.y); u.z = f2bf(v.z); u.w = f2bf(v.w);
    *reinterpret_cast<ushort4*>(dst + base) = u;
  }
}

// ---------------- timestep embedding MLP ----------------
__global__ void k_temb1(const float* __restrict__ tsf, const float* __restrict__ w1,
                        const float* __restrict__ b1, float* __restrict__ h1tT){
  int o = blockIdx.x, b = threadIdx.x;  // 1024 x 64
  float t = tsf[b];
  float acc = b1[o];
  const float c = -9.210340371976184f / 160.0f;  // -ln(10000)/160
  for (int j = 0; j < 160; ++j) {
    float arg = t * expf(c * (float)j);
    acc += w1[(size_t)o * T_ + j] * cosf(arg) + w1[(size_t)o * T_ + 160 + j] * sinf(arg);
  }
  float s = acc / (1.0f + expf(-acc));
  h1tT[(size_t)o * B_ + b] = s;
}

__global__ void k_temb2(const float* __restrict__ h1tT, const float* __restrict__ w2,
                        const float* __restrict__ b2, float* __restrict__ temb){
  int o = blockIdx.x, b = threadIdx.x;  // 1024 x 64
  float acc = b2[o];
  for (int d = 0; d < D_; ++d) acc += h1tT[(size_t)d * B_ + b] * w2[(size_t)o * D_ + d];
  temb[(size_t)b * D_ + o] = acc;
}

__global__ void k_silu(const float* __restrict__ in, u16* __restrict__ outb, int n){
  int i = blockIdx.x * blockDim.x + threadIdx.x;
  if (i < n) { float x = in[i]; outb[i] = f2bf(x / (1.0f + expf(-x))); }
}

__global__ void k_init_lat(const float* __restrict__ latents, float* __restrict__ lat){
  int i = blockIdx.x * blockDim.x + threadIdx.x;
  if (i < BQ_ * D_) lat[i] = latents[i & (Q_ * D_ - 1)];
}

// ---------------- row LayerNorm (no affine), bf16 -> bf16 ----------------
__global__ __launch_bounds__(256) void k_rownorm(const u16* __restrict__ xp, u16* __restrict__ outb){
  __shared__ float s1[4], s2[4];
  size_t row = blockIdx.x;
  int tid = threadIdx.x;
  ushort4 u = reinterpret_cast<const ushort4*>(xp + row * D_)[tid];
  float v0 = bf2f(u.x), v1 = bf2f(u.y), v2 = bf2f(u.z), v3 = bf2f(u.w);
  float s = v0 + v1 + v2 + v3;
  float q = v0 * v0 + v1 * v1 + v2 * v2 + v3 * v3;
  for (int off = 32; off; off >>= 1) { s += __shfl_down(s, off); q += __shfl_down(q, off); }
  if ((tid & 63) == 0) { s1[tid >> 6] = s; s2[tid >> 6] = q; }
  __syncthreads();
  float S = s1[0] + s1[1] + s1[2] + s1[3], Qv = s2[0] + s2[1] + s2[2] + s2[3];
  float mean = S * (1.f / D_);
  float rs = rsqrtf(Qv * (1.f / D_) - mean * mean + 1e-5f);
  ushort4 o;
  o.x = f2bf((v0 - mean) * rs); o.y = f2bf((v1 - mean) * rs);
  o.z = f2bf((v2 - mean) * rs); o.w = f2bf((v3 - mean) * rs);
  reinterpret_cast<ushort4*>(outb + row * D_)[tid] = o;
}

// ---------------- LayerNorm + AdaLN modulation, fp32 -> bf16 ----------------
__global__ __launch_bounds__(256) void k_lnmod(const float* __restrict__ in, const float* __restrict__ g,
                                               const float* __restrict__ bb, const float* __restrict__ modp,
                                               int mstride, u16* __restrict__ outb){
  __shared__ float s1[4], s2[4];
  int row = blockIdx.x, tid = threadIdx.x;
  int b = row >> 4;
  float4 v = reinterpret_cast<const float4*>(in + (size_t)row * D_)[tid];
  float s = v.x + v.y + v.z + v.w;
  float q = v.x * v.x + v.y * v.y + v.z * v.z + v.w * v.w;
  for (int off = 32; off; off >>= 1) { s += __shfl_down(s, off); q += __shfl_down(q, off); }
  if ((tid & 63) == 0) { s1[tid >> 6] = s; s2[tid >> 6] = q; }
  __syncthreads();
  float S = s1[0] + s1[1] + s1[2] + s1[3], Qv = s2[0] + s2[1] + s2[2] + s2[3];
  float mean = S * (1.f / D_);
  float rs = rsqrtf(Qv * (1.f / D_) - mean * mean + 1e-5f);
  float4 gg = reinterpret_cast<const float4*>(g)[tid];
  float4 bv = reinterpret_cast<const float4*>(bb)[tid];
  const float* mrow = modp + (size_t)b * mstride;
  float4 sh = reinterpret_cast<const float4*>(mrow)[tid];
  float4 scv = reinterpret_cast<const float4*>(mrow + D_)[tid];
  ushort4 o;
  o.x = f2bf(((v.x - mean) * rs * gg.x + bv.x) * (1.f + scv.x) + sh.x);
  o.y = f2bf(((v.y - mean) * rs * gg.y + bv.y) * (1.f + scv.y) + sh.y);
  o.z = f2bf(((v.z - mean) * rs * gg.z + bv.z) * (1.f + scv.z) + sh.z);
  o.w = f2bf(((v.w - mean) * rs * gg.w + bv.w) * (1.f + scv.w) + sh.w);
  reinterpret_cast<ushort4*>(outb + (size_t)row * D_)[tid] = o;
}

// ---------------- final LayerNorm (affine), fp32 -> fp32 out ----------------
__global__ __launch_bounds__(256) void k_lnfinal(const float* __restrict__ in, const float* __restrict__ g,
                                                 const float* __restrict__ bb, float* __restrict__ outf){
  __shared__ float s1[4], s2[4];
  int row = blockIdx.x, tid = threadIdx.x;
  float4 v = reinterpret_cast<const float4*>(in + (size_t)row * O_)[tid];
  float s = v.x + v.y + v.z + v.w;
  float q = v.x * v.x + v.y * v.y + v.z * v.z + v.w * v.w;
  for (int off = 32; off; off >>= 1) { s += __shfl_down(s, off); q += __shfl_down(q, off); }
  if ((tid & 63) == 0) { s1[tid >> 6] = s; s2[tid >> 6] = q; }
  __syncthreads();
  float S = s1[0] + s1[1] + s1[2] + s1[3], Qv = s2[0] + s2[1] + s2[2] + s2[3];
  float mean = S * (1.f / O_);
  float rs = rsqrtf(Qv * (1.f / O_) - mean * mean + 1e-5f);
  float4 gg = reinterpret_cast<const float4*>(g)[tid];
  float4 bv = reinterpret_cast<const float4*>(bb)[tid];
  float4 o;
  o.x = (v.x - mean) * rs * gg.x + bv.x;
  o.y = (v.y - mean) * rs * gg.y + bv.y;
  o.z = (v.z - mean) * rs * gg.z + bv.z;
  o.w = (v.w - mean) * rs * gg.w + bv.w;
  reinterpret_cast<float4*>(outf + (size_t)row * O_)[tid] = o;
}

// ---------------- attention v3: head-major K/V, LDS-tiled QK^T AND PV ----------------
__global__ __launch_bounds__(256) void k_attn2(const u16* __restrict__ qb,
                                               const u16* __restrict__ kb,
                                               const u16* __restrict__ vb,
                                               u16* __restrict__ ob){
  __shared__ float qs[Q_][DH_ + 4];
  __shared__ u16   ks[128][DH_ + 4];   // K tile, reused as V tile in PV phase
  __shared__ float sc[Q_][600];
  __shared__ float rsum[Q_];
  const int bh  = blockIdx.x;           // b*16 + h
  const int b   = bh >> 4, h = bh & 15;
  const int tid = threadIdx.x;
  {
    int qi = tid >> 4, d4 = (tid & 15) << 2;
    ushort4 u = *reinterpret_cast<const ushort4*>(qb + (size_t)(b * Q_ + qi) * D_ + h * DH_ + d4);
    qs[qi][d4 + 0] = 0.125f * bf2f(u.x);   // sc*sc = 1/sqrt(DH) folded into Q
    qs[qi][d4 + 1] = 0.125f * bf2f(u.y);
    qs[qi][d4 + 2] = 0.125f * bf2f(u.z);
    qs[qi][d4 + 3] = 0.125f * bf2f(u.w);
  }
  const u16* kbh = kb + (size_t)bh * KL_ * DH_;
  const u16* vbh = vb + (size_t)bh * KL_ * DH_;
  for (int j0 = 0; j0 < KL_; j0 += 128) {
    int rows = KL_ - j0; if (rows > 128) rows = 128;
    __syncthreads();
    for (int idx = tid; idx < rows * 16; idx += 256) {
      int r = idx >> 4, c4 = (idx & 15) << 2;
      *reinterpret_cast<ushort4*>(&ks[r][c4]) =
          *reinterpret_cast<const ushort4*>(kbh + (size_t)(j0 + r) * DH_ + c4);
    }
    __syncthreads();
    for (int e = tid; e < Q_ * 128; e += 256) {
      int jj = e & 127, qi = e >> 7;
      if (jj < rows) {
        float s = 0.f;
        #pragma unroll
        for (int d = 0; d < DH_; d += 4) {
          ushort4 u = *reinterpret_cast<const ushort4*>(&ks[jj][d]);
          s += qs[qi][d] * bf2f(u.x) + qs[qi][d + 1] * bf2f(u.y)
             + qs[qi][d + 2] * bf2f(u.z) + qs[qi][d + 3] * bf2f(u.w);
        }
        sc[qi][j0 + jj] = s;
      }
    }
  }
  __syncthreads();
  {
    int g = tid >> 4, l = tid & 15;
    float mx = -1e30f;
    for (int j = l; j < KL_; j += 16) mx = fmaxf(mx, sc[g][j]);
    for (int m = 1; m < 16; m <<= 1) mx = fmaxf(mx, __shfl_xor(mx, m));
    float sum = 0.f;
    for (int j = l; j < KL_; j += 16) { float e = expf(sc[g][j] - mx); sc[g][j] = e; sum += e; }
    for (int m = 1; m < 16; m <<= 1) sum += __shfl_xor(sum, m);
    if (l == 0) rsum[g] = sum;
  }
  // PV phase: stage V tiles in LDS (reuse ks), accumulate
  {
    int d = tid & 63, q0 = tid >> 6;
    float acc[4] = {0.f, 0.f, 0.f, 0.f};
    for (int j0 = 0; j0 < KL_; j0 += 128) {
      int rows = KL_ - j0; if (rows > 128) rows = 128;
      __syncthreads();
      for (int idx = tid; idx < rows * 16; idx += 256) {
        int r = idx >> 4, c4 = (idx & 15) << 2;
        *reinterpret_cast<ushort4*>(&ks[r][c4]) =
            *reinterpret_cast<const ushort4*>(vbh + (size_t)(j0 + r) * DH_ + c4);
      }
      __syncthreads();
      for (int jj = 0; jj < rows; ++jj) {
        float vj = bf2f(ks[jj][d]);
        #pragma unroll
        for (int t = 0; t < 4; ++t) acc[t] += sc[q0 + t * 4][j0 + jj] * vj;
      }
    }
    #pragma unroll
    for (int t = 0; t < 4; ++t) {
      int qi = q0 + t * 4;
      ob[(size_t)(b * Q_ + qi) * D_ + h * DH_ + d] = f2bf(acc[t] / rsum[qi]);
    }
  }
}

// ---------------- host ----------------
static void conv_launch(const float* src, u16* dst, size_t n, hipStream_t s){
  long long n4 = (long long)(n >> 2);
  int blocks = (int)((n4 + 255) / 256);
  if (blocks > 4096) blocks = 4096;
  k_f2b<<<blocks, 256, 0, s>>>(src, dst, n4);
}

template<int EPI, int BM, int BN>
static void gemm(const u16* X, const u16* W, const float* bias, const float* aux,
                 void* out, void* out2, int M, int N, int K, hipStream_t s, int ksplit = 1){
  dim3 g(N / BN, (M + BM - 1) / BM, ksplit);
  k_gemm<EPI, BM, BN><<<g, 256, 0, s>>>(X, W, bias, aux, out, out2, M, N, K / ksplit, K);
}

extern "C" void kernel_launch(void* const* d_in, const int* in_sizes, int n_in,
                              void* d_out, int out_size, void* d_ws, size_t ws_size,
                              hipStream_t stream)
{
  const float* x         = (const float*)d_in[0];
  const int*   tsp       = (const int*)  d_in[1];
  const float* latents   = (const float*)d_in[2];
  const float* proj_in_w = (const float*)d_in[3];
  const float* proj_in_b = (const float*)d_in[4];
  const float* time_w1   = (const float*)d_in[5];
  const float* time_b1   = (const float*)d_in[6];
  const float* time_w2   = (const float*)d_in[7];
  const float* time_b2   = (const float*)d_in[8];
  const float* ln1_g     = (const float*)d_in[9];
  const float* ln1_b     = (const float*)d_in[10];
  const float* ln2_g     = (const float*)d_in[11];
  const float* ln2_b     = (const float*)d_in[12];
  const float* q_w       = (const float*)d_in[13];
  const float* kv_w      = (const float*)d_in[14];
  const float* out_w     = (const float*)d_in[15];
  const float* ffln_g    = (const float*)d_in[16];
  const float* ffln_b    = (const float*)d_in[17];
  const float* ff_w1     = (const float*)d_in[18];
  const float* ff_w2     = (const float*)d_in[19];
  const float* ada_w     = (const float*)d_in[20];
  const float* ada_b     = (const float*)d_in[21];
  const float* proj_out_w= (const float*)d_in[22];
  const float* proj_out_b= (const float*)d_in[23];
  const float* nout_g    = (const float*)d_in[24];
  const float* nout_b    = (const float*)d_in[25];

  char* Wp = (char*)d_ws;
  size_t off = 0;
  auto alloc = [&](size_t bytes) -> void* {
    void* p = Wp + off;
    off = (off + bytes + 255) & ~(size_t)255;
    return p;
  };

  float* tsf   = (float*)alloc((size_t)B_ * 4);
  float* temb  = (float*)alloc((size_t)B_ * D_ * 4);
  float* h1tT  = (float*)alloc((size_t)D_ * B_ * 4);
  u16*   stemb = (u16*)  alloc((size_t)B_ * D_ * 2);
  float* modb8 = (float*)alloc((size_t)B_ * L_ * 4 * D_ * 4);   // [64][32768] all layers
  float* kvb   = (float*)alloc((size_t)2 * D_ * 4);
  float* lat   = (float*)alloc((size_t)BQ_ * D_ * 4);
  u16*   lt    = (u16*)  alloc((size_t)BQ_ * D_ * 2);
  u16*   qb    = (u16*)  alloc((size_t)BQ_ * D_ * 2);
  u16*   ob    = (u16*)  alloc((size_t)BQ_ * D_ * 2);
  u16*   hb    = (u16*)  alloc((size_t)BQ_ * D_ * 2);
  u16*   h1b   = (u16*)  alloc((size_t)BQ_ * FF_ * 2);
  u16*   latb  = (u16*)  alloc((size_t)BQ_ * D_ * 2);
  float* tmpf  = (float*)alloc((size_t)BQ_ * D_ * 4);
  u16*   wpin  = (u16*)  alloc((size_t)D_ * E_ * 2);
  u16*   wada8 = (u16*)  alloc((size_t)L_ * 4 * D_ * D_ * 2);   // all layers, bf16
  u16*   wpout = (u16*)  alloc((size_t)O_ * D_ * 2);
  u16*   kvf   = (u16*)  alloc((size_t)2 * D_ * D_ * 2);
  u16*   wqkv  = (u16*)  alloc((size_t)3 * D_ * D_ * 2);   // [q_w ; kv_w] stacked bf16
  u16*   wouti = (u16*)  alloc((size_t)D_ * D_ * 2);
  u16*   wff1i = (u16*)  alloc((size_t)FF_ * D_ * 2);
  u16*   wff2i = (u16*)  alloc((size_t)D_ * FF_ * 2);
  u16*   nxp   = (u16*)  alloc((size_t)MX_ * D_ * 2);
  u16*   kvwb  = wqkv + (size_t)D_ * D_;                   // rows 1024..3071 of wqkv
  // big region: prologue [xb | xpb], layer loop [kbuf | vbuf] (disjoint lifetimes)
  size_t xb_sz  = (size_t)B_ * N_ * E_ * 2;
  size_t xpb_sz = (size_t)MX_ * D_ * 2;
  size_t kv_sz  = (size_t)B_ * H_ * KL_ * DH_ * 2;
  size_t big_sz = (xb_sz + xpb_sz > 2 * kv_sz) ? (xb_sz + xpb_sz) : 2 * kv_sz;
  char* big = (char*)alloc(big_sz);
  u16* xb   = (u16*)big;
  u16* xpb  = (u16*)(big + xb_sz);
  u16* kbuf = (u16*)big;
  u16* vbuf = (u16*)(big + kv_sz);   // == kbuf + KVOFF elements

  // ---- weight / input conversions (layer-invariant) ----
  conv_launch(x,          xb,    (size_t)B_ * N_ * E_, stream);
  conv_launch(proj_in_w,  wpin,  (size_t)D_ * E_,      stream);
  conv_launch(proj_out_w, wpout, (size_t)O_ * D_,      stream);
  conv_launch(ada_w,      wada8, (size_t)L_ * 4 * D_ * D_, stream);

  // ---- timestep embedding ----
  k_tsnorm<<<1, B_, 0, stream>>>(tsp, tsf);
  k_temb1<<<D_, B_, 0, stream>>>(tsf, time_w1, time_b1, h1tT);
  k_temb2<<<D_, B_, 0, stream>>>(h1tT, time_w2, time_b2, temb);
  k_silu<<<(B_ * D_ + 255) / 256, 256, 0, stream>>>(temb, stemb, B_ * D_);

  // ---- AdaLN mod for ALL layers in one GEMM: [64, 32768] ----
  gemm<2, 64, 64>(stemb, wada8, ada_b, nullptr, modb8, nullptr, B_, L_ * 4 * D_, D_, stream);

  // ---- proj_in + temb ----
  gemm<3, 128, 128>(xb, wpin, proj_in_b, temb, xpb, nullptr, MX_, D_, E_, stream);
  k_rownorm<<<MX_, 256, 0, stream>>>(xpb, nxp);
  k_init_lat<<<(BQ_ * D_) / 256, 256, 0, stream>>>(latents, lat);

  const int MSTR = L_ * 4 * D_;   // 32768: per-batch row stride in modb8
  for (int i = 0; i < L_; ++i) {
    // fused per-layer weight prep (fold + 4 conversions)
    k_prep<<<12288, 256, 0, stream>>>(
        kv_w + (size_t)i * 2 * D_ * D_, ln1_g + i * D_, ln1_b + i * D_,
        kvf, kvwb, kvb,
        q_w   + (size_t)i * D_ * D_,  wqkv,
        out_w + (size_t)i * D_ * D_,  wouti,
        ff_w1 + (size_t)i * FF_ * D_, wff1i,
        ff_w2 + (size_t)i * D_ * FF_, wff2i);

    // kv over x tokens (dominant GEMM) -> head-major K/V, LN1 folded into weights
    gemm<6, 128, 128>(nxp, kvf, kvb, nullptr, nullptr, kbuf, MX_, 2 * D_, D_, stream);
    // modulated latents
    k_lnmod<<<BQ_, 256, 0, stream>>>(lat, ln2_g + i * D_, ln2_b + i * D_,
                                     modb8 + (size_t)i * 4 * D_, MSTR, lt);
    // merged q-proj + latent-kv: N = 3072
    gemm<8, 64, 64>(lt, wqkv, nullptr, nullptr, qb, kbuf, BQ_, 3 * D_, D_, stream);
    k_attn2<<<B_ * H_, 256, 0, stream>>>(qb, kbuf, vbuf, ob);
    gemm<4, 64, 64>(ob, wouti, nullptr, lat, lat, nullptr, BQ_, D_, D_, stream);
    // FFN
    k_lnmod<<<BQ_, 256, 0, stream>>>(lat, ffln_g + i * D_, ffln_b + i * D_,
                                     modb8 + (size_t)i * 4 * D_ + 2 * D_, MSTR, hb);
    gemm<5, 64, 64>(hb, wff1i, nullptr, nullptr, h1b, nullptr, BQ_, FF_, D_, stream);
    // ff2 split-K=4: 256 -> 1024 blocks (1 -> 4 blocks/CU); partials atomicAdd into lat
    gemm<9, 64, 64>(h1b, wff2i, nullptr, nullptr, lat, nullptr, BQ_, D_, FF_, stream, 4);
  }
  // bf16 copy of final latents for the output projection
  conv_launch(lat, latb, (size_t)BQ_ * D_, stream);

  // ---- output projection + final LN (fp32 output) ----
  gemm<2, 64, 64>(latb, wpout, proj_out_b, nullptr, tmpf, nullptr, BQ_, O_, D_, stream);
  k_lnfinal<<<BQ_, 256, 0, stream>>>(tmpf, nout_g, nout_b, (float*)d_out);
}